// Round 7
// baseline (174.493 us; speedup 1.0000x reference)
//
#include <hip/hip_runtime.h>
#include <hip/hip_bf16.h>

#define G_      4
#define NVP     3000
#define NCP     1000
#define DEG     8
#define NV      (G_*NVP)      // 12000
#define NC      (G_*NCP)      // 4000
#define NN      (NV+NC)       // 16000
#define NE      (NV*DEG)      // 96000
#define EPG     (NVP*DEG)     // 24000 edges per graph
#define DF      64
#define DH      128
#define DO      64
#define KB      8
#define NB      (G_*KB)       // 32 break nodes
#define MAXR    96
#define MAXJ    640
#define FWD2_GEMM_BLOCKS (NV/32)   // 375

// ---------------- fused setup: count/scan/fill/nodeval/topk, one block per graph ----------------
// (no sort — corr_a is value-keyed; LDS-atomic fill order only perturbs ulp-level sum order)
__global__ __launch_bounds__(1024) void k_setup(const int* __restrict__ conArr,
    int* __restrict__ csr_off, int* __restrict__ csr_v,
    float* __restrict__ dinvC_g, float* __restrict__ nodeval, int* __restrict__ breakix)
{
    __shared__ int   cnt[NCP];
    __shared__ int   cur[NCP];
    __shared__ float dinvC[NCP];
    __shared__ float nvl[NVP + NCP];
    __shared__ int   wsum[16];
    __shared__ float mv[16]; __shared__ int mp[16];

    int g = blockIdx.x, tid = threadIdx.x, lane = tid & 63, w = tid >> 6;
    int ebase = g * EPG, cb = g * NCP;
    const float dv3 = 1.0f/3.0f;

    // count (LDS histogram)
    if (tid < NCP) cnt[tid] = 0;
    __syncthreads();
    for (int e = tid; e < EPG; e += 1024)
        atomicAdd(&cnt[conArr[ebase + e] - cb], 1);
    __syncthreads();
    // graph-local exclusive scan (edges of graph g are contiguous in [ebase, ebase+EPG))
    int x = (tid < NCP) ? cnt[tid] : 0;
    int orig = x;
    for (int o = 1; o < 64; o <<= 1) { int y = __shfl_up(x, o); if (lane >= o) x += y; }
    if (lane == 63) wsum[w] = x;
    __syncthreads();
    if (tid == 0) { int run = 0; for (int t = 0; t < 16; ++t) { int z = wsum[t]; wsum[t] = run; run += z; } }
    __syncthreads();
    int excl = x - orig + wsum[w];
    if (tid < NCP) {
        cur[tid] = excl;
        csr_off[cb + tid] = ebase + excl;
        float dc = 1.0f / sqrtf((float)(orig + 1));
        dinvC[tid] = dc;
        dinvC_g[cb + tid] = dc;
        float nvc = (float)orig * (dc * dv3) + dc*dc;
        nvl[NVP + tid] = nvc;
        nodeval[NV + cb + tid] = nvc;
    }
    if (g == 0 && tid == 0) csr_off[NC] = NE;
    __syncthreads();
    // fill (LDS-atomic position, scattered global write; fire-and-forget)
    for (int e = tid; e < EPG; e += 1024) {
        int c = conArr[ebase + e] - cb;
        int p = atomicAdd(&cur[c], 1);
        csr_v[ebase + p] = (ebase + e) >> 3;   // global var id
    }
    // variable nodeval (LDS dinvC gathers)
    for (int v = tid; v < NVP; v += 1024) {
        float s = 0.f;
        int e0 = ebase + v*DEG;
        #pragma unroll
        for (int k = 0; k < DEG; ++k) s += dv3 * dinvC[conArr[e0+k] - cb];
        float val = s + dv3*dv3;
        nvl[v] = val;
        nodeval[g*NVP + v] = val;
    }
    __syncthreads();
    // top-8, tie -> lower local position (matches lax.top_k)
    for (int it = 0; it < KB; ++it) {
        float bv = -1e30f; int bp = 1 << 30;
        for (int p = tid; p < NVP+NCP; p += 1024) {
            float vv = nvl[p];
            if (vv > bv || (vv == bv && p < bp)) { bv = vv; bp = p; }
        }
        for (int o = 32; o > 0; o >>= 1) {
            float ov = __shfl_xor(bv, o); int op = __shfl_xor(bp, o);
            if (ov > bv || (ov == bv && op < bp)) { bv = ov; bp = op; }
        }
        if (lane == 0) { mv[w] = bv; mp[w] = bp; }
        __syncthreads();
        if (tid == 0) {
            float fv = mv[0]; int fp = mp[0];
            for (int t = 1; t < 16; ++t)
                if (mv[t] > fv || (mv[t] == fv && mp[t] < fp)) { fv = mv[t]; fp = mp[t]; }
            nvl[fp] = -1e30f;
            breakix[g*KB + it] = (fp < NVP) ? (g*NVP + fp) : (NV + g*NCP + (fp - NVP));
        }
        __syncthreads();
    }
}

// ---------------- fwd1: fused spmmX + gemm1 -> S1 (NN x 128), AX never materialized ----------------
__global__ __launch_bounds__(256) void k_fwd1(const float* __restrict__ vf, const float* __restrict__ cf,
    const float* __restrict__ dinvC, const int* __restrict__ conArr,
    const int* __restrict__ csr_off, const int* __restrict__ csr_v,
    const float* __restrict__ W1, const float* __restrict__ b1,
    const float* __restrict__ nodeval, float* __restrict__ S1)
{
    __shared__ float W1T[128*68];   // [c][k] transposed, padded
    __shared__ float AXs[32*68];
    int tid = threadIdx.x, lane = tid & 63, w = tid >> 6;
    const float dv3 = 1.0f/3.0f;
    for (int t = tid; t < 64*128; t += 256) {
        int k = t >> 7, c = t & 127;
        W1T[c*68 + k] = W1[t];
    }
    int r0 = blockIdx.x * 32;
    // stage 8 rows per wave of A_hat @ X  (4 waves x 8 rows = 32)
    for (int rr = w*8; rr < w*8 + 8; ++rr) {
        int row = r0 + rr;
        float acc;
        if (row < NV) {
            acc = dv3 * vf[(size_t)row*DF + lane];
            int e0 = row*DEG;
            #pragma unroll
            for (int k = 0; k < DEG; ++k) {
                int c = conArr[e0+k];
                acc += dinvC[c] * cf[(size_t)c*DF + lane];
            }
            acc *= dv3;
        } else {
            int c = row - NV;
            float di = dinvC[c];
            acc = di * cf[(size_t)c*DF + lane];
            int p0 = csr_off[c], p1 = csr_off[c+1];
            int len = p1 - p0;
            int myv = (p0 + lane < p1) ? csr_v[p0 + lane] : 0;
            int lim = len < 64 ? len : 64;
            for (int m = 0; m < lim; ++m) {
                int v = __shfl(myv, m);
                acc += dv3 * vf[(size_t)v*DF + lane];
            }
            for (int p = p0 + 64; p < p1; ++p)        // defensive tail
                acc += dv3 * vf[(size_t)csr_v[p]*DF + lane];
            acc *= di;
        }
        AXs[rr*68 + lane] = acc;
    }
    __syncthreads();
    int tc = tid & 15, tr = tid >> 4;
    float acc[2][8];
    #pragma unroll
    for (int r = 0; r < 2; ++r)
        #pragma unroll
        for (int j = 0; j < 8; ++j) acc[r][j] = 0.f;
    #pragma unroll
    for (int k0 = 0; k0 < 64; k0 += 4) {
        float4 a0 = *(const float4*)&AXs[(tr*2+0)*68 + k0];
        float4 a1 = *(const float4*)&AXs[(tr*2+1)*68 + k0];
        #pragma unroll
        for (int j = 0; j < 8; ++j) {
            float4 wv = *(const float4*)&W1T[(tc + 16*j)*68 + k0];
            acc[0][j] += a0.x*wv.x + a0.y*wv.y + a0.z*wv.z + a0.w*wv.w;
            acc[1][j] += a1.x*wv.x + a1.y*wv.y + a1.z*wv.z + a1.w*wv.w;
        }
    }
    #pragma unroll
    for (int r = 0; r < 2; ++r) {
        int row = r0 + tr*2 + r;
        float nv_ = nodeval[row];
        #pragma unroll
        for (int j = 0; j < 8; ++j) {
            int col = tc + 16*j;
            S1[(size_t)row*DH + col] = acc[r][j] + nv_*b1[col];
        }
    }
}

// ---------------- fwd2: blocks [0,375) fused spmmH+gemm2+LN; blocks [375,407) corr_a ----------------
__global__ __launch_bounds__(256) void k_fwd2(const float* __restrict__ S1,
    const float* __restrict__ dinvC, const int* __restrict__ conArr,
    const int* __restrict__ csr_off, const int* __restrict__ csr_v,
    const float* __restrict__ W1, const float* __restrict__ W2,
    const float* __restrict__ b2, const float* __restrict__ nodeval,
    const float* __restrict__ gamma, const float* __restrict__ beta,
    const int* __restrict__ breakidx,
    float* __restrict__ outvar, float* __restrict__ holo, float* __restrict__ out,
    int* __restrict__ RnG, float* __restrict__ RwG, int* __restrict__ nRG,
    float* __restrict__ dz2G)
{
    __shared__ float smem[14848];   // 59392 B, aliased per role
    __shared__ int nR_s;
    int tid = threadIdx.x, lane = tid & 63, w = tid >> 6;
    const float dv3 = 1.0f/3.0f;

    if (blockIdx.x < FWD2_GEMM_BLOCKS) {
        float* W2T = smem;          // 64 x 132
        float* AHs = smem + 8448;   // 32 x 132
        float* s2  = smem + 12672;  // 32 x 68
        for (int t = tid; t < 128*64; t += 256) {
            int k = t >> 6, c = t & 63;
            W2T[c*132 + k] = W2[t];
        }
        int r0 = blockIdx.x * 32;
        // 4 waves x 8 rows = 32 rows
        for (int rr = w*8; rr < w*8 + 8; ++rr) {
            int v = r0 + rr;
            float a0 = dv3 * fmaxf(S1[(size_t)v*DH + lane], 0.f);
            float a1 = dv3 * fmaxf(S1[(size_t)v*DH + 64 + lane], 0.f);
            int e0 = v*DEG;
            #pragma unroll
            for (int k = 0; k < DEG; ++k) {
                int c = conArr[e0+k];
                float dc = dinvC[c];
                a0 += dc * fmaxf(S1[(size_t)(NV+c)*DH + lane], 0.f);
                a1 += dc * fmaxf(S1[(size_t)(NV+c)*DH + 64 + lane], 0.f);
            }
            AHs[rr*132 + lane]      = dv3 * a0;
            AHs[rr*132 + 64 + lane] = dv3 * a1;
        }
        __syncthreads();
        int tc = tid & 15, tr = tid >> 4;
        float acc[2][4];
        #pragma unroll
        for (int r = 0; r < 2; ++r)
            #pragma unroll
            for (int j = 0; j < 4; ++j) acc[r][j] = 0.f;
        #pragma unroll
        for (int k0 = 0; k0 < 128; k0 += 4) {
            float4 a0 = *(const float4*)&AHs[(tr*2+0)*132 + k0];
            float4 a1 = *(const float4*)&AHs[(tr*2+1)*132 + k0];
            #pragma unroll
            for (int j = 0; j < 4; ++j) {
                float4 wv = *(const float4*)&W2T[(tc + 16*j)*132 + k0];
                acc[0][j] += a0.x*wv.x + a0.y*wv.y + a0.z*wv.z + a0.w*wv.w;
                acc[1][j] += a1.x*wv.x + a1.y*wv.y + a1.z*wv.z + a1.w*wv.w;
            }
        }
        #pragma unroll
        for (int r = 0; r < 2; ++r) {
            int row = tr*2 + r;
            float nv_ = nodeval[r0 + row];
            #pragma unroll
            for (int j = 0; j < 4; ++j) {
                int col = tc + 16*j;
                s2[row*68 + col] = acc[r][j] + nv_*b2[col];
            }
        }
        __syncthreads();
        float gm = gamma[lane], bt = beta[lane];
        for (int rr = 0; rr < 8; ++rr) {
            int row = w*8 + rr;
            int v = r0 + row;
            float xv = s2[row*68 + lane];
            float s = xv;
            for (int o = 32; o > 0; o >>= 1) s += __shfl_xor(s, o);
            float mu = s * (1.f/64.f);
            float d = xv - mu;
            float vs = d*d;
            for (int o = 32; o > 0; o >>= 1) vs += __shfl_xor(vs, o);
            float rstd = 1.0f / sqrtf(vs*(1.f/64.f) + 1e-5f);
            float h = d*rstd*gm + bt;
            outvar[(size_t)v*DO + lane] = xv;
            holo  [(size_t)v*DO + lane] = h;
            out   [(size_t)v*DO + lane] = h;
        }
    } else {
        // ---- corr_a role ----
        float* W2s = smem;              // 128 x 64
        float* dh  = smem + 8192;       // 4 x 128
        float* Rw  = smem + 8704;       // MAXR
        int*   Rn  = (int*)(smem + 8800); // MAXR
        int b = blockIdx.x - FWD2_GEMM_BLOCKS;
        int i = breakidx[b];
        for (int t = tid; t < 128*64; t += 256) W2s[t] = W2[t];
        if (tid < 64) {
            if (i >= NV) {
                int c = i - NV;
                float di = dinvC[c];
                int p0 = csr_off[c], len = csr_off[c+1] - p0;
                if (len <= 64) {
                    int v = (lane < len) ? csr_v[p0 + lane] : 0x7fffffff;
                    int firstLane = 64, mult = 0;
                    for (int m = 0; m < 64; ++m) {
                        int vm = __shfl(v, m);
                        if (vm == v) { mult++; if (m < firstLane) firstLane = m; }
                    }
                    bool head = (lane < len) && (firstLane == lane);
                    unsigned long long hmask = __ballot(head);
                    int hrk = 0;
                    for (int m = 0; m < 64; ++m) {
                        if (!((hmask >> m) & 1)) continue;
                        int vm = __shfl(v, m);
                        if (vm < v) hrk++;
                    }
                    if (head) { Rn[hrk] = v; Rw[hrk] = (float)mult * (dv3 * di); }
                    int nH = __popcll(hmask);
                    if (lane == 0) { Rn[nH] = i; Rw[nH] = di*di; nR_s = nH + 1; }
                } else if (lane == 0) {
                    int n = 0;
                    for (int p = p0; p < p0 + len; ++p) {
                        int v = csr_v[p]; int f = -1;
                        for (int q = 0; q < n; ++q) if (Rn[q] == v) { f = q; break; }
                        if (f >= 0) Rw[f] += dv3 * di;
                        else if (n < MAXR-1) { Rn[n] = v; Rw[n] = dv3 * di; ++n; }
                    }
                    Rn[n] = i; Rw[n] = di*di; nR_s = n + 1;
                }
            } else if (lane == 0) {
                float di = dv3;
                int cn[DEG];
                for (int k = 0; k < DEG; ++k) cn[k] = NV + conArr[i*DEG + k];
                for (int a = 1; a < DEG; ++a) { int key = cn[a]; int bb = a-1;
                    while (bb >= 0 && cn[bb] > key) { cn[bb+1] = cn[bb]; --bb; } cn[bb+1] = key; }
                int n = 0, k = 0;
                while (k < DEG) { int u = cn[k]; int m = 1; ++k;
                    while (k < DEG && cn[k] == u) { ++m; ++k; }
                    Rn[n] = u; Rw[n] = (float)m * dinvC[u - NV] * di; ++n; }
                Rn[n] = i; Rw[n] = di*di; nR_s = n + 1;
            }
        }
        __syncthreads();
        int nR = nR_s;
        for (int t = tid; t < nR; t += 256) { RnG[b*MAXR + t] = Rn[t]; RwG[b*MAXR + t] = Rw[t]; }
        if (tid == 0) nRG[b] = nR;
        for (int r0 = 0; r0 < nR; r0 += 4) {
            __syncthreads();
            for (int t = tid; t < 512; t += 256) {
                int ty = t >> 7, k = t & 127;
                int r = r0 + ty;
                if (r < nR) {
                    float s1 = S1[(size_t)Rn[r]*DH + k];
                    float a = s1 + Rw[r] * W1[64*128 + k];
                    dh[ty*128 + k] = fmaxf(a, 0.f) - fmaxf(s1, 0.f);
                }
            }
            __syncthreads();
            int ty2 = tid >> 6, c2 = tid & 63;
            int r2 = r0 + ty2;
            if (r2 < nR) {
                float accv = 0.f;
                #pragma unroll
                for (int kk = 0; kk < 128; ++kk) accv += dh[ty2*128 + kk] * W2s[kk*64 + c2];
                dz2G[((size_t)b*MAXR + r2)*DO + c2] = accv;
            }
        }
    }
}

// ---------------- corr_b: per graph serial over its 8 breaks ----------------
__global__ void k_corr_b(const int* __restrict__ RnG, const float* __restrict__ RwG,
                         const int* __restrict__ nRG, const float* __restrict__ dz2G,
                         const int* __restrict__ breakidx, const float* __restrict__ dinvC,
                         const int* __restrict__ conArr, const int* __restrict__ csr_off,
                         const int* __restrict__ csr_v,
                         const float* __restrict__ outvar, const float* __restrict__ holo,
                         const float* __restrict__ gamma, const float* __restrict__ beta,
                         float* __restrict__ out) {
    int g = blockIdx.x;
    int lane = threadIdx.x & 63, wv = threadIdx.x >> 6; // 16 waves
    const float dv3 = 1.0f/3.0f;
    __shared__ int Jn[MAXJ];
    __shared__ int nJ_s;
    for (int bi = 0; bi < KB; ++bi) {
        int b = g*KB + bi;
        int i = breakidx[b];
        int nR = nRG[b];
        if (i >= NV) {
            int nJ = nR - 1;
            const float* dzi = &dz2G[((size_t)b*MAXR + (nR-1))*DO];
            for (int j0 = wv; j0 < nJ; j0 += 16) {
                int j = RnG[b*MAXR + j0];
                float aji = RwG[b*MAXR + j0];
                float x = outvar[(size_t)j*DO + lane]
                        + aji * dzi[lane]
                        + dv3*dv3 * dz2G[((size_t)b*MAXR + j0)*DO + lane];
                float s = x; for (int o = 32; o > 0; o >>= 1) s += __shfl_xor(s, o);
                float mu = s * (1.f/64.f);
                float d = x - mu;
                float vs = d*d; for (int o = 32; o > 0; o >>= 1) vs += __shfl_xor(vs, o);
                float rstd = 1.0f / sqrtf(vs*(1.f/64.f) + 1e-5f);
                float hn = d*rstd*gamma[lane] + beta[lane];
                out[(size_t)j*DO + lane] += 0.125f * (hn - holo[(size_t)j*DO + lane]);
            }
        } else {
            if (threadIdx.x == 0) {
                int n = 0; Jn[n++] = i;
                for (int r = 0; r < nR-1; ++r) {
                    int c = RnG[b*MAXR + r] - NV;
                    for (int p = csr_off[c]; p < csr_off[c+1]; ++p) {
                        int u = csr_v[p];
                        bool found = false;
                        for (int q = 0; q < n; ++q) if (Jn[q] == u) { found = true; break; }
                        if (!found && n < MAXJ) Jn[n++] = u;
                    }
                }
                nJ_s = n;
            }
            __syncthreads();
            int nJ = nJ_s;
            for (int j0 = wv; j0 < nJ; j0 += 16) {
                int j = Jn[j0];
                float x = outvar[(size_t)j*DO + lane];
                for (int k = 0; k < DEG; ++k) {
                    int cn = NV + conArr[j*DEG + k];
                    for (int r = 0; r < nR-1; ++r)
                        if (RnG[b*MAXR + r] == cn) {
                            x += dv3 * dinvC[cn - NV] * dz2G[((size_t)b*MAXR + r)*DO + lane];
                            break;
                        }
                }
                if (j == i) x += dv3*dv3 * dz2G[((size_t)b*MAXR + nR-1)*DO + lane];
                float s = x; for (int o = 32; o > 0; o >>= 1) s += __shfl_xor(s, o);
                float mu = s * (1.f/64.f);
                float d = x - mu;
                float vs = d*d; for (int o = 32; o > 0; o >>= 1) vs += __shfl_xor(vs, o);
                float rstd = 1.0f / sqrtf(vs*(1.f/64.f) + 1e-5f);
                float hn = d*rstd*gamma[lane] + beta[lane];
                out[(size_t)j*DO + lane] += 0.125f * (hn - holo[(size_t)j*DO + lane]);
            }
        }
        __syncthreads();
    }
}

// ---------------- launch ----------------

extern "C" void kernel_launch(void* const* d_in, const int* in_sizes, int n_in,
                              void* d_out, int out_size, void* d_ws, size_t ws_size,
                              hipStream_t stream) {
    const float* vf    = (const float*)d_in[0];
    const float* cf    = (const float*)d_in[1];
    const float* W1    = (const float*)d_in[2];
    const float* b1    = (const float*)d_in[3];
    const float* W2    = (const float*)d_in[4];
    const float* b2    = (const float*)d_in[5];
    const float* gamma = (const float*)d_in[6];
    const float* beta  = (const float*)d_in[7];
    const int*   ei    = (const int*)d_in[8];   // [0..NE) = con, [NE..2NE) = var
    const int*   conArr = ei;
    float* out = (float*)d_out;

    char* ws = (char*)d_ws;
    size_t off = 0;
    auto alloc = [&](size_t bytes) { char* p = ws + off; off = (off + bytes + 255) & ~(size_t)255; return p; };
    float* dinvC   = (float*)alloc(NC*4);
    int*   csr_off = (int*)  alloc((NC+1)*4);
    int*   csr_v   = (int*)  alloc(NE*4);
    float* nodeval = (float*)alloc(NN*4);
    int*   breakix = (int*)  alloc(NB*4);
    float* S1      = (float*)alloc((size_t)NN*DH*4);
    float* outvar  = (float*)alloc((size_t)NV*DO*4);
    float* holo    = (float*)alloc((size_t)NV*DO*4);
    int*   RnG     = (int*)  alloc(NB*MAXR*4);
    float* RwG     = (float*)alloc(NB*MAXR*4);
    int*   nRG     = (int*)  alloc(NB*4);
    float* dz2G    = (float*)alloc((size_t)NB*MAXR*DO*4);

    k_setup <<<G_, 1024, 0, stream>>>(conArr, csr_off, csr_v, dinvC, nodeval, breakix);
    k_fwd1  <<<NN/32, 256, 0, stream>>>(vf, cf, dinvC, conArr, csr_off, csr_v, W1, b1, nodeval, S1);
    k_fwd2  <<<FWD2_GEMM_BLOCKS + NB, 256, 0, stream>>>(S1, dinvC, conArr, csr_off, csr_v,
                                       W1, W2, b2, nodeval, gamma, beta, breakix,
                                       outvar, holo, out, RnG, RwG, nRG, dz2G);
    k_corr_b<<<G_, 1024, 0, stream>>>(RnG, RwG, nRG, dz2G, breakix, dinvC, conArr,
                                      csr_off, csr_v, outvar, holo, gamma, beta, out);
}

// Round 8
// 130.560 us; speedup vs baseline: 1.3365x; 1.3365x over previous
//
#include <hip/hip_runtime.h>
#include <hip/hip_bf16.h>

#define G_      4
#define NVP     3000
#define NCP     1000
#define DEG     8
#define NV      (G_*NVP)      // 12000
#define NC      (G_*NCP)      // 4000
#define NN      (NV+NC)       // 16000
#define NE      (NV*DEG)      // 96000
#define EPG     (NVP*DEG)     // 24000 edges per graph
#define DF      64
#define DH      128
#define DO      64
#define KB      8
#define NB      (G_*KB)       // 32 break nodes
#define MAXR    96
#define MAXJ    640
#define FWD2_GEMM_BLOCKS (NV/32)   // 375

// ---------------- fused setup: count/scan/fill/nodeval/topk, one block per graph ----------------
__global__ __launch_bounds__(1024) void k_setup(const int* __restrict__ conArr,
    int* __restrict__ csr_off, int* __restrict__ csr_v,
    float* __restrict__ dinvC_g, float* __restrict__ nodeval, int* __restrict__ breakix)
{
    __shared__ int   cnt[NCP];
    __shared__ int   cur[NCP];
    __shared__ float dinvC[NCP];
    __shared__ float nvl[NVP + NCP];
    __shared__ int   wsum[16];
    __shared__ float mv[16]; __shared__ int mp[16];

    int g = blockIdx.x, tid = threadIdx.x, lane = tid & 63, w = tid >> 6;
    int ebase = g * EPG, cb = g * NCP;
    const float dv3 = 1.0f/3.0f;

    if (tid < NCP) cnt[tid] = 0;
    __syncthreads();
    for (int e = tid; e < EPG; e += 1024)
        atomicAdd(&cnt[conArr[ebase + e] - cb], 1);
    __syncthreads();
    int x = (tid < NCP) ? cnt[tid] : 0;
    int orig = x;
    for (int o = 1; o < 64; o <<= 1) { int y = __shfl_up(x, o); if (lane >= o) x += y; }
    if (lane == 63) wsum[w] = x;
    __syncthreads();
    if (tid == 0) { int run = 0; for (int t = 0; t < 16; ++t) { int z = wsum[t]; wsum[t] = run; run += z; } }
    __syncthreads();
    int excl = x - orig + wsum[w];
    if (tid < NCP) {
        cur[tid] = excl;
        csr_off[cb + tid] = ebase + excl;
        float dc = 1.0f / sqrtf((float)(orig + 1));
        dinvC[tid] = dc;
        dinvC_g[cb + tid] = dc;
        float nvc = (float)orig * (dc * dv3) + dc*dc;
        nvl[NVP + tid] = nvc;
        nodeval[NV + cb + tid] = nvc;
    }
    if (g == 0 && tid == 0) csr_off[NC] = NE;
    __syncthreads();
    for (int e = tid; e < EPG; e += 1024) {
        int c = conArr[ebase + e] - cb;
        int p = atomicAdd(&cur[c], 1);
        csr_v[ebase + p] = (ebase + e) >> 3;   // global var id
    }
    for (int v = tid; v < NVP; v += 1024) {
        float s = 0.f;
        int e0 = ebase + v*DEG;
        #pragma unroll
        for (int k = 0; k < DEG; ++k) s += dv3 * dinvC[conArr[e0+k] - cb];
        float val = s + dv3*dv3;
        nvl[v] = val;
        nodeval[g*NVP + v] = val;
    }
    __syncthreads();
    for (int it = 0; it < KB; ++it) {
        float bv = -1e30f; int bp = 1 << 30;
        for (int p = tid; p < NVP+NCP; p += 1024) {
            float vv = nvl[p];
            if (vv > bv || (vv == bv && p < bp)) { bv = vv; bp = p; }
        }
        for (int o = 32; o > 0; o >>= 1) {
            float ov = __shfl_xor(bv, o); int op = __shfl_xor(bp, o);
            if (ov > bv || (ov == bv && op < bp)) { bv = ov; bp = op; }
        }
        if (lane == 0) { mv[w] = bv; mp[w] = bp; }
        __syncthreads();
        if (tid == 0) {
            float fv = mv[0]; int fp = mp[0];
            for (int t = 1; t < 16; ++t)
                if (mv[t] > fv || (mv[t] == fv && mp[t] < fp)) { fv = mv[t]; fp = mp[t]; }
            nvl[fp] = -1e30f;
            breakix[g*KB + it] = (fp < NVP) ? (g*NVP + fp) : (NV + g*NCP + (fp - NVP));
        }
        __syncthreads();
    }
}

// ---------------- spmmX: AX = A_hat @ X, one row per wave (max gather parallelism) ----------------
__global__ void k_spmmX(const float* __restrict__ vf, const float* __restrict__ cf,
                        const float* __restrict__ dinvC, const int* __restrict__ conArr,
                        const int* __restrict__ csr_off, const int* __restrict__ csr_v,
                        float* __restrict__ AX)
{
    int i = blockIdx.x*4 + (threadIdx.x >> 6);
    int lane = threadIdx.x & 63;
    const float dv3 = 1.0f/3.0f;
    float acc, di;
    if (i < NV) {
        di = dv3;
        acc = dv3 * vf[(size_t)i*DF + lane];
        int e0 = i*DEG;
        #pragma unroll
        for (int k = 0; k < DEG; ++k) {
            int c = conArr[e0+k];
            acc += dinvC[c] * cf[(size_t)c*DF + lane];
        }
    } else {
        int c = i - NV;
        di = dinvC[c];
        float base = di * cf[(size_t)c*DF + lane];
        int p0 = csr_off[c], p1 = csr_off[c+1];
        int len = p1 - p0;
        int myv = (p0 + lane < p1) ? csr_v[p0 + lane] : 0;
        int lim = len < 64 ? len : 64;
        float a0 = 0.f, a1 = 0.f, a2 = 0.f, a3 = 0.f;
        int m = 0;
        for (; m + 4 <= lim; m += 4) {
            int v0 = __shfl(myv, m+0);
            int v1 = __shfl(myv, m+1);
            int v2 = __shfl(myv, m+2);
            int v3 = __shfl(myv, m+3);
            a0 += vf[(size_t)v0*DF + lane];
            a1 += vf[(size_t)v1*DF + lane];
            a2 += vf[(size_t)v2*DF + lane];
            a3 += vf[(size_t)v3*DF + lane];
        }
        for (; m < lim; ++m) { int v = __shfl(myv, m); a0 += vf[(size_t)v*DF + lane]; }
        for (int p = p0 + 64; p < p1; ++p) a0 += vf[(size_t)csr_v[p]*DF + lane]; // defensive
        acc = base + dv3 * ((a0 + a1) + (a2 + a3));
    }
    AX[(size_t)i*DF + lane] = di * acc;
}

// ---------------- gemm1: S1 = AX @ W1 + nodeval (x) b1  (NN x 128), dense staging ----------------
__global__ __launch_bounds__(256) void k_gemm1(const float* __restrict__ AX, const float* __restrict__ W1,
                        const float* __restrict__ b1, const float* __restrict__ nodeval,
                        float* __restrict__ S1)
{
    __shared__ float W1T[128*68];   // [c][k], padded
    __shared__ float AXs[32*68];
    int tid = threadIdx.x;
    for (int t = tid; t < 64*128; t += 256) {
        int k = t >> 7, c = t & 127;
        W1T[c*68 + k] = W1[t];
    }
    int r0 = blockIdx.x * 32;
    for (int t = tid; t < 32*16; t += 256) {
        int row = t >> 4, q = t & 15;
        *(float4*)&AXs[row*68 + q*4] = *(const float4*)&AX[(size_t)(r0+row)*DF + q*4];
    }
    __syncthreads();
    int tc = tid & 15, tr = tid >> 4;
    float acc[2][8];
    #pragma unroll
    for (int r = 0; r < 2; ++r)
        #pragma unroll
        for (int j = 0; j < 8; ++j) acc[r][j] = 0.f;
    #pragma unroll
    for (int k0 = 0; k0 < 64; k0 += 4) {
        float4 a0 = *(const float4*)&AXs[(tr*2+0)*68 + k0];
        float4 a1 = *(const float4*)&AXs[(tr*2+1)*68 + k0];
        #pragma unroll
        for (int j = 0; j < 8; ++j) {
            float4 wv = *(const float4*)&W1T[(tc + 16*j)*68 + k0];
            acc[0][j] += a0.x*wv.x + a0.y*wv.y + a0.z*wv.z + a0.w*wv.w;
            acc[1][j] += a1.x*wv.x + a1.y*wv.y + a1.z*wv.z + a1.w*wv.w;
        }
    }
    #pragma unroll
    for (int r = 0; r < 2; ++r) {
        int row = r0 + tr*2 + r;
        float nv_ = nodeval[row];
        #pragma unroll
        for (int j = 0; j < 8; ++j) {
            int col = tc + 16*j;
            S1[(size_t)row*DH + col] = acc[r][j] + nv_*b1[col];
        }
    }
}

// ---------------- spmmH: AH = A_hat @ relu(S1) at variable rows (NV x 128) ----------------
__global__ void k_spmmH(const float* __restrict__ S1, const float* __restrict__ dinvC,
                        const int* __restrict__ conArr, float* __restrict__ AH)
{
    int v = blockIdx.x*2 + (threadIdx.x >> 7);
    int ch = threadIdx.x & 127;
    const float dv3 = 1.0f/3.0f;
    float acc = dv3 * fmaxf(S1[(size_t)v*DH + ch], 0.f);
    int e0 = v*DEG;
    #pragma unroll
    for (int k = 0; k < DEG; ++k) {
        int c = conArr[e0+k];
        acc += dinvC[c] * fmaxf(S1[(size_t)(NV + c)*DH + ch], 0.f);
    }
    AH[(size_t)v*DH + ch] = dv3 * acc;
}

// ---------------- fwd2: blocks [0,375) gemm2+LN (dense AH); blocks [375,407) corr_a ----------------
__global__ __launch_bounds__(256) void k_fwd2(const float* __restrict__ S1,
    const float* __restrict__ AH,
    const float* __restrict__ dinvC, const int* __restrict__ conArr,
    const int* __restrict__ csr_off, const int* __restrict__ csr_v,
    const float* __restrict__ W1, const float* __restrict__ W2,
    const float* __restrict__ b2, const float* __restrict__ nodeval,
    const float* __restrict__ gamma, const float* __restrict__ beta,
    const int* __restrict__ breakidx,
    float* __restrict__ outvar, float* __restrict__ holo, float* __restrict__ out,
    int* __restrict__ RnG, float* __restrict__ RwG, int* __restrict__ nRG,
    float* __restrict__ dz2G)
{
    __shared__ float smem[14848];   // 59392 B, aliased per role
    __shared__ int nR_s;
    int tid = threadIdx.x, lane = tid & 63, w = tid >> 6;
    const float dv3 = 1.0f/3.0f;

    if (blockIdx.x < FWD2_GEMM_BLOCKS) {
        float* W2T = smem;          // 64 x 132
        float* AHs = smem + 8448;   // 32 x 132
        float* s2  = smem + 12672;  // 32 x 68
        for (int t = tid; t < 128*64; t += 256) {
            int k = t >> 6, c = t & 63;
            W2T[c*132 + k] = W2[t];
        }
        int r0 = blockIdx.x * 32;
        for (int t = tid; t < 32*32; t += 256) {
            int row = t >> 5, q = t & 31;
            *(float4*)&AHs[row*132 + q*4] = *(const float4*)&AH[(size_t)(r0+row)*DH + q*4];
        }
        __syncthreads();
        int tc = tid & 15, tr = tid >> 4;
        float acc[2][4];
        #pragma unroll
        for (int r = 0; r < 2; ++r)
            #pragma unroll
            for (int j = 0; j < 4; ++j) acc[r][j] = 0.f;
        #pragma unroll
        for (int k0 = 0; k0 < 128; k0 += 4) {
            float4 a0 = *(const float4*)&AHs[(tr*2+0)*132 + k0];
            float4 a1 = *(const float4*)&AHs[(tr*2+1)*132 + k0];
            #pragma unroll
            for (int j = 0; j < 4; ++j) {
                float4 wv = *(const float4*)&W2T[(tc + 16*j)*132 + k0];
                acc[0][j] += a0.x*wv.x + a0.y*wv.y + a0.z*wv.z + a0.w*wv.w;
                acc[1][j] += a1.x*wv.x + a1.y*wv.y + a1.z*wv.z + a1.w*wv.w;
            }
        }
        #pragma unroll
        for (int r = 0; r < 2; ++r) {
            int row = tr*2 + r;
            float nv_ = nodeval[r0 + row];
            #pragma unroll
            for (int j = 0; j < 4; ++j) {
                int col = tc + 16*j;
                s2[row*68 + col] = acc[r][j] + nv_*b2[col];
            }
        }
        __syncthreads();
        float gm = gamma[lane], bt = beta[lane];
        for (int rr = 0; rr < 8; ++rr) {
            int row = w*8 + rr;
            int v = r0 + row;
            float xv = s2[row*68 + lane];
            float s = xv;
            for (int o = 32; o > 0; o >>= 1) s += __shfl_xor(s, o);
            float mu = s * (1.f/64.f);
            float d = xv - mu;
            float vs = d*d;
            for (int o = 32; o > 0; o >>= 1) vs += __shfl_xor(vs, o);
            float rstd = 1.0f / sqrtf(vs*(1.f/64.f) + 1e-5f);
            float h = d*rstd*gm + bt;
            outvar[(size_t)v*DO + lane] = xv;
            holo  [(size_t)v*DO + lane] = h;
            out   [(size_t)v*DO + lane] = h;
        }
    } else {
        // ---- corr_a role ----
        float* W2s = smem;                // 128 x 64
        float* dh  = smem + 8192;         // 4 x 128
        float* Rw  = smem + 8704;         // MAXR
        int*   Rn  = (int*)(smem + 8800); // MAXR
        int b = blockIdx.x - FWD2_GEMM_BLOCKS;
        int i = breakidx[b];
        for (int t = tid; t < 128*64; t += 256) W2s[t] = W2[t];
        if (tid < 64) {
            if (i >= NV) {
                int c = i - NV;
                float di = dinvC[c];
                int p0 = csr_off[c], len = csr_off[c+1] - p0;
                if (len <= 64) {
                    int v = (lane < len) ? csr_v[p0 + lane] : 0x7fffffff;
                    int firstLane = 64, mult = 0;
                    for (int m = 0; m < 64; ++m) {
                        int vm = __shfl(v, m);
                        if (vm == v) { mult++; if (m < firstLane) firstLane = m; }
                    }
                    bool head = (lane < len) && (firstLane == lane);
                    unsigned long long hmask = __ballot(head);
                    int hrk = 0;
                    for (int m = 0; m < 64; ++m) {
                        if (!((hmask >> m) & 1)) continue;
                        int vm = __shfl(v, m);
                        if (vm < v) hrk++;
                    }
                    if (head) { Rn[hrk] = v; Rw[hrk] = (float)mult * (dv3 * di); }
                    int nH = __popcll(hmask);
                    if (lane == 0) { Rn[nH] = i; Rw[nH] = di*di; nR_s = nH + 1; }
                } else if (lane == 0) {
                    int n = 0;
                    for (int p = p0; p < p0 + len; ++p) {
                        int v = csr_v[p]; int f = -1;
                        for (int q = 0; q < n; ++q) if (Rn[q] == v) { f = q; break; }
                        if (f >= 0) Rw[f] += dv3 * di;
                        else if (n < MAXR-1) { Rn[n] = v; Rw[n] = dv3 * di; ++n; }
                    }
                    Rn[n] = i; Rw[n] = di*di; nR_s = n + 1;
                }
            } else if (lane == 0) {
                float di = dv3;
                int cn[DEG];
                for (int k = 0; k < DEG; ++k) cn[k] = NV + conArr[i*DEG + k];
                for (int a = 1; a < DEG; ++a) { int key = cn[a]; int bb = a-1;
                    while (bb >= 0 && cn[bb] > key) { cn[bb+1] = cn[bb]; --bb; } cn[bb+1] = key; }
                int n = 0, k = 0;
                while (k < DEG) { int u = cn[k]; int m = 1; ++k;
                    while (k < DEG && cn[k] == u) { ++m; ++k; }
                    Rn[n] = u; Rw[n] = (float)m * dinvC[u - NV] * di; ++n; }
                Rn[n] = i; Rw[n] = di*di; nR_s = n + 1;
            }
        }
        __syncthreads();
        int nR = nR_s;
        for (int t = tid; t < nR; t += 256) { RnG[b*MAXR + t] = Rn[t]; RwG[b*MAXR + t] = Rw[t]; }
        if (tid == 0) nRG[b] = nR;
        for (int r0 = 0; r0 < nR; r0 += 4) {
            __syncthreads();
            for (int t = tid; t < 512; t += 256) {
                int ty = t >> 7, k = t & 127;
                int r = r0 + ty;
                if (r < nR) {
                    float s1 = S1[(size_t)Rn[r]*DH + k];
                    float a = s1 + Rw[r] * W1[64*128 + k];
                    dh[ty*128 + k] = fmaxf(a, 0.f) - fmaxf(s1, 0.f);
                }
            }
            __syncthreads();
            int ty2 = tid >> 6, c2 = tid & 63;
            int r2 = r0 + ty2;
            if (r2 < nR) {
                float accv = 0.f;
                #pragma unroll
                for (int kk = 0; kk < 128; ++kk) accv += dh[ty2*128 + kk] * W2s[kk*64 + c2];
                dz2G[((size_t)b*MAXR + r2)*DO + c2] = accv;
            }
        }
    }
}

// ---------------- corr_b: per graph serial over its 8 breaks ----------------
__global__ void k_corr_b(const int* __restrict__ RnG, const float* __restrict__ RwG,
                         const int* __restrict__ nRG, const float* __restrict__ dz2G,
                         const int* __restrict__ breakidx, const float* __restrict__ dinvC,
                         const int* __restrict__ conArr, const int* __restrict__ csr_off,
                         const int* __restrict__ csr_v,
                         const float* __restrict__ outvar, const float* __restrict__ holo,
                         const float* __restrict__ gamma, const float* __restrict__ beta,
                         float* __restrict__ out) {
    int g = blockIdx.x;
    int lane = threadIdx.x & 63, wv = threadIdx.x >> 6; // 16 waves
    const float dv3 = 1.0f/3.0f;
    __shared__ int Jn[MAXJ];
    __shared__ int nJ_s;
    for (int bi = 0; bi < KB; ++bi) {
        int b = g*KB + bi;
        int i = breakidx[b];
        int nR = nRG[b];
        if (i >= NV) {
            int nJ = nR - 1;
            const float* dzi = &dz2G[((size_t)b*MAXR + (nR-1))*DO];
            for (int j0 = wv; j0 < nJ; j0 += 16) {
                int j = RnG[b*MAXR + j0];
                float aji = RwG[b*MAXR + j0];
                float x = outvar[(size_t)j*DO + lane]
                        + aji * dzi[lane]
                        + dv3*dv3 * dz2G[((size_t)b*MAXR + j0)*DO + lane];
                float s = x; for (int o = 32; o > 0; o >>= 1) s += __shfl_xor(s, o);
                float mu = s * (1.f/64.f);
                float d = x - mu;
                float vs = d*d; for (int o = 32; o > 0; o >>= 1) vs += __shfl_xor(vs, o);
                float rstd = 1.0f / sqrtf(vs*(1.f/64.f) + 1e-5f);
                float hn = d*rstd*gamma[lane] + beta[lane];
                out[(size_t)j*DO + lane] += 0.125f * (hn - holo[(size_t)j*DO + lane]);
            }
        } else {
            if (threadIdx.x == 0) {
                int n = 0; Jn[n++] = i;
                for (int r = 0; r < nR-1; ++r) {
                    int c = RnG[b*MAXR + r] - NV;
                    for (int p = csr_off[c]; p < csr_off[c+1]; ++p) {
                        int u = csr_v[p];
                        bool found = false;
                        for (int q = 0; q < n; ++q) if (Jn[q] == u) { found = true; break; }
                        if (!found && n < MAXJ) Jn[n++] = u;
                    }
                }
                nJ_s = n;
            }
            __syncthreads();
            int nJ = nJ_s;
            for (int j0 = wv; j0 < nJ; j0 += 16) {
                int j = Jn[j0];
                float x = outvar[(size_t)j*DO + lane];
                for (int k = 0; k < DEG; ++k) {
                    int cn = NV + conArr[j*DEG + k];
                    for (int r = 0; r < nR-1; ++r)
                        if (RnG[b*MAXR + r] == cn) {
                            x += dv3 * dinvC[cn - NV] * dz2G[((size_t)b*MAXR + r)*DO + lane];
                            break;
                        }
                }
                if (j == i) x += dv3*dv3 * dz2G[((size_t)b*MAXR + nR-1)*DO + lane];
                float s = x; for (int o = 32; o > 0; o >>= 1) s += __shfl_xor(s, o);
                float mu = s * (1.f/64.f);
                float d = x - mu;
                float vs = d*d; for (int o = 32; o > 0; o >>= 1) vs += __shfl_xor(vs, o);
                float rstd = 1.0f / sqrtf(vs*(1.f/64.f) + 1e-5f);
                float hn = d*rstd*gamma[lane] + beta[lane];
                out[(size_t)j*DO + lane] += 0.125f * (hn - holo[(size_t)j*DO + lane]);
            }
        }
        __syncthreads();
    }
}

// ---------------- launch ----------------

extern "C" void kernel_launch(void* const* d_in, const int* in_sizes, int n_in,
                              void* d_out, int out_size, void* d_ws, size_t ws_size,
                              hipStream_t stream) {
    const float* vf    = (const float*)d_in[0];
    const float* cf    = (const float*)d_in[1];
    const float* W1    = (const float*)d_in[2];
    const float* b1    = (const float*)d_in[3];
    const float* W2    = (const float*)d_in[4];
    const float* b2    = (const float*)d_in[5];
    const float* gamma = (const float*)d_in[6];
    const float* beta  = (const float*)d_in[7];
    const int*   ei    = (const int*)d_in[8];   // [0..NE) = con, [NE..2NE) = var
    const int*   conArr = ei;
    float* out = (float*)d_out;

    char* ws = (char*)d_ws;
    size_t off = 0;
    auto alloc = [&](size_t bytes) { char* p = ws + off; off = (off + bytes + 255) & ~(size_t)255; return p; };
    float* dinvC   = (float*)alloc(NC*4);
    int*   csr_off = (int*)  alloc((NC+1)*4);
    int*   csr_v   = (int*)  alloc(NE*4);
    float* nodeval = (float*)alloc(NN*4);
    int*   breakix = (int*)  alloc(NB*4);
    float* AX      = (float*)alloc((size_t)NN*DF*4);
    float* S1      = (float*)alloc((size_t)NN*DH*4);
    float* AH      = (float*)alloc((size_t)NV*DH*4);
    float* outvar  = (float*)alloc((size_t)NV*DO*4);
    float* holo    = (float*)alloc((size_t)NV*DO*4);
    int*   RnG     = (int*)  alloc(NB*MAXR*4);
    float* RwG     = (float*)alloc(NB*MAXR*4);
    int*   nRG     = (int*)  alloc(NB*4);
    float* dz2G    = (float*)alloc((size_t)NB*MAXR*DO*4);

    k_setup <<<G_, 1024, 0, stream>>>(conArr, csr_off, csr_v, dinvC, nodeval, breakix);
    k_spmmX <<<NN/4, 256, 0, stream>>>(vf, cf, dinvC, conArr, csr_off, csr_v, AX);
    k_gemm1 <<<NN/32, 256, 0, stream>>>(AX, W1, b1, nodeval, S1);
    k_spmmH <<<NV/2, 256, 0, stream>>>(S1, dinvC, conArr, AH);
    k_fwd2  <<<FWD2_GEMM_BLOCKS + NB, 256, 0, stream>>>(S1, AH, dinvC, conArr, csr_off, csr_v,
                                       W1, W2, b2, nodeval, gamma, beta, breakix,
                                       outvar, holo, out, RnG, RwG, nRG, dz2G);
    k_corr_b<<<G_, 1024, 0, stream>>>(RnG, RwG, nRG, dz2G, breakix, dinvC, conArr,
                                      csr_off, csr_v, outvar, holo, gamma, beta, out);
}

// Round 9
// 108.209 us; speedup vs baseline: 1.6126x; 1.2066x over previous
//
#include <hip/hip_runtime.h>
#include <hip/hip_bf16.h>

#define G_      4
#define NVP     3000
#define NCP     1000
#define DEG     8
#define NV      (G_*NVP)      // 12000
#define NC      (G_*NCP)      // 4000
#define NN      (NV+NC)       // 16000
#define NE      (NV*DEG)      // 96000
#define EPG     (NVP*DEG)     // 24000 edges per graph
#define DF      64
#define DH      128
#define DO      64
#define KB      8
#define NB      (G_*KB)       // 32 break nodes
#define MAXR    96
#define MAXJ    640
#define FWD2_GEMM_BLOCKS (NV/32)   // 375

// ---------------- setup: count/scan/dinv/nodeval/topk (graph-local, 4 blocks); fill split out ----------------
__global__ __launch_bounds__(1024) void k_setup(const int* __restrict__ conArr,
    int* __restrict__ csr_off, int* __restrict__ csr_cur,
    float* __restrict__ dinvC_g, float* __restrict__ nodeval, int* __restrict__ breakix)
{
    __shared__ int   cnt[NCP];
    __shared__ float dinvC[NCP];
    __shared__ float nvl[NVP + NCP];
    __shared__ int   wsum[16];
    __shared__ float mv[16]; __shared__ int mp[16];

    int g = blockIdx.x, tid = threadIdx.x, lane = tid & 63, w = tid >> 6;
    int ebase = g * EPG, cb = g * NCP;
    const float dv3 = 1.0f/3.0f;

    if (tid < NCP) cnt[tid] = 0;
    __syncthreads();
    for (int e = tid; e < EPG; e += 1024)
        atomicAdd(&cnt[conArr[ebase + e] - cb], 1);
    __syncthreads();
    int x = (tid < NCP) ? cnt[tid] : 0;
    int orig = x;
    for (int o = 1; o < 64; o <<= 1) { int y = __shfl_up(x, o); if (lane >= o) x += y; }
    if (lane == 63) wsum[w] = x;
    __syncthreads();
    if (tid == 0) { int run = 0; for (int t = 0; t < 16; ++t) { int z = wsum[t]; wsum[t] = run; run += z; } }
    __syncthreads();
    int excl = x - orig + wsum[w];
    if (tid < NCP) {
        csr_off[cb + tid] = ebase + excl;
        csr_cur[cb + tid] = ebase + excl;
        float dc = 1.0f / sqrtf((float)(orig + 1));
        dinvC[tid] = dc;
        dinvC_g[cb + tid] = dc;
        float nvc = (float)orig * (dc * dv3) + dc*dc;
        nvl[NVP + tid] = nvc;
        nodeval[NV + cb + tid] = nvc;
    }
    if (g == 0 && tid == 0) csr_off[NC] = NE;
    __syncthreads();
    for (int v = tid; v < NVP; v += 1024) {
        float s = 0.f;
        int e0 = ebase + v*DEG;
        #pragma unroll
        for (int k = 0; k < DEG; ++k) s += dv3 * dinvC[conArr[e0+k] - cb];
        float val = s + dv3*dv3;
        nvl[v] = val;
        nodeval[g*NVP + v] = val;
    }
    __syncthreads();
    for (int it = 0; it < KB; ++it) {
        float bv = -1e30f; int bp = 1 << 30;
        for (int p = tid; p < NVP+NCP; p += 1024) {
            float vv = nvl[p];
            if (vv > bv || (vv == bv && p < bp)) { bv = vv; bp = p; }
        }
        for (int o = 32; o > 0; o >>= 1) {
            float ov = __shfl_xor(bv, o); int op = __shfl_xor(bp, o);
            if (ov > bv || (ov == bv && op < bp)) { bv = ov; bp = op; }
        }
        if (lane == 0) { mv[w] = bv; mp[w] = bp; }
        __syncthreads();
        if (tid == 0) {
            float fv = mv[0]; int fp = mp[0];
            for (int t = 1; t < 16; ++t)
                if (mv[t] > fv || (mv[t] == fv && mp[t] < fp)) { fv = mv[t]; fp = mp[t]; }
            nvl[fp] = -1e30f;
            breakix[g*KB + it] = (fp < NVP) ? (g*NVP + fp) : (NV + g*NCP + (fp - NVP));
        }
        __syncthreads();
    }
}

// ---------------- fill: chip-wide scattered CSR fill (global atomics; order -> ulp only) ----------------
__global__ __launch_bounds__(1024) void k_fill(const int* __restrict__ conArr,
                                               int* __restrict__ csr_cur,
                                               int* __restrict__ csr_v) {
    int e = blockIdx.x*1024 + threadIdx.x;
    if (e < NE) { int p = atomicAdd(&csr_cur[conArr[e]], 1); csr_v[p] = e >> 3; }
}

// ---------------- spmmX: AX = A_hat @ X, one row per wave ----------------
__global__ void k_spmmX(const float* __restrict__ vf, const float* __restrict__ cf,
                        const float* __restrict__ dinvC, const int* __restrict__ conArr,
                        const int* __restrict__ csr_off, const int* __restrict__ csr_v,
                        float* __restrict__ AX)
{
    int i = blockIdx.x*4 + (threadIdx.x >> 6);
    int lane = threadIdx.x & 63;
    const float dv3 = 1.0f/3.0f;
    float acc, di;
    if (i < NV) {
        di = dv3;
        acc = dv3 * vf[(size_t)i*DF + lane];
        int e0 = i*DEG;
        #pragma unroll
        for (int k = 0; k < DEG; ++k) {
            int c = conArr[e0+k];
            acc += dinvC[c] * cf[(size_t)c*DF + lane];
        }
    } else {
        int c = i - NV;
        di = dinvC[c];
        float base = di * cf[(size_t)c*DF + lane];
        int p0 = csr_off[c], p1 = csr_off[c+1];
        int len = p1 - p0;
        int myv = (p0 + lane < p1) ? csr_v[p0 + lane] : 0;
        int lim = len < 64 ? len : 64;
        float a0 = 0.f, a1 = 0.f, a2 = 0.f, a3 = 0.f;
        int m = 0;
        for (; m + 4 <= lim; m += 4) {
            int v0 = __shfl(myv, m+0);
            int v1 = __shfl(myv, m+1);
            int v2 = __shfl(myv, m+2);
            int v3 = __shfl(myv, m+3);
            a0 += vf[(size_t)v0*DF + lane];
            a1 += vf[(size_t)v1*DF + lane];
            a2 += vf[(size_t)v2*DF + lane];
            a3 += vf[(size_t)v3*DF + lane];
        }
        for (; m < lim; ++m) { int v = __shfl(myv, m); a0 += vf[(size_t)v*DF + lane]; }
        for (int p = p0 + 64; p < p1; ++p) a0 += vf[(size_t)csr_v[p]*DF + lane]; // defensive
        acc = base + dv3 * ((a0 + a1) + (a2 + a3));
    }
    AX[(size_t)i*DF + lane] = di * acc;
}

// ---------------- gemm1: S1 = AX @ W1 + nodeval (x) b1  (NN x 128) ----------------
__global__ __launch_bounds__(256) void k_gemm1(const float* __restrict__ AX, const float* __restrict__ W1,
                        const float* __restrict__ b1, const float* __restrict__ nodeval,
                        float* __restrict__ S1)
{
    __shared__ float W1T[128*68];   // [c][k], padded
    __shared__ float AXs[32*68];
    int tid = threadIdx.x;
    for (int t = tid; t < 64*128; t += 256) {
        int k = t >> 7, c = t & 127;
        W1T[c*68 + k] = W1[t];
    }
    int r0 = blockIdx.x * 32;
    for (int t = tid; t < 32*16; t += 256) {
        int row = t >> 4, q = t & 15;
        *(float4*)&AXs[row*68 + q*4] = *(const float4*)&AX[(size_t)(r0+row)*DF + q*4];
    }
    __syncthreads();
    int tc = tid & 15, tr = tid >> 4;
    float acc[2][8];
    #pragma unroll
    for (int r = 0; r < 2; ++r)
        #pragma unroll
        for (int j = 0; j < 8; ++j) acc[r][j] = 0.f;
    #pragma unroll
    for (int k0 = 0; k0 < 64; k0 += 4) {
        float4 a0 = *(const float4*)&AXs[(tr*2+0)*68 + k0];
        float4 a1 = *(const float4*)&AXs[(tr*2+1)*68 + k0];
        #pragma unroll
        for (int j = 0; j < 8; ++j) {
            float4 wv = *(const float4*)&W1T[(tc + 16*j)*68 + k0];
            acc[0][j] += a0.x*wv.x + a0.y*wv.y + a0.z*wv.z + a0.w*wv.w;
            acc[1][j] += a1.x*wv.x + a1.y*wv.y + a1.z*wv.z + a1.w*wv.w;
        }
    }
    #pragma unroll
    for (int r = 0; r < 2; ++r) {
        int row = r0 + tr*2 + r;
        float nv_ = nodeval[row];
        #pragma unroll
        for (int j = 0; j < 8; ++j) {
            int col = tc + 16*j;
            S1[(size_t)row*DH + col] = acc[r][j] + nv_*b1[col];
        }
    }
}

// ---------------- spmmH: AH = A_hat @ relu(S1) at variable rows (NV x 128) ----------------
__global__ void k_spmmH(const float* __restrict__ S1, const float* __restrict__ dinvC,
                        const int* __restrict__ conArr, float* __restrict__ AH)
{
    int v = blockIdx.x*2 + (threadIdx.x >> 7);
    int ch = threadIdx.x & 127;
    const float dv3 = 1.0f/3.0f;
    float acc = dv3 * fmaxf(S1[(size_t)v*DH + ch], 0.f);
    int e0 = v*DEG;
    #pragma unroll
    for (int k = 0; k < DEG; ++k) {
        int c = conArr[e0+k];
        acc += dinvC[c] * fmaxf(S1[(size_t)(NV + c)*DH + ch], 0.f);
    }
    AH[(size_t)v*DH + ch] = dv3 * acc;
}

// ---------------- fwd2: blocks [0,375) gemm2+LN; blocks [375,407) corr_a ----------------
__global__ __launch_bounds__(256) void k_fwd2(const float* __restrict__ S1,
    const float* __restrict__ AH,
    const float* __restrict__ dinvC, const int* __restrict__ conArr,
    const int* __restrict__ csr_off, const int* __restrict__ csr_v,
    const float* __restrict__ W1, const float* __restrict__ W2,
    const float* __restrict__ b2, const float* __restrict__ nodeval,
    const float* __restrict__ gamma, const float* __restrict__ beta,
    const int* __restrict__ breakidx,
    float* __restrict__ outvar, float* __restrict__ holo, float* __restrict__ out,
    int* __restrict__ RnG, float* __restrict__ RwG, int* __restrict__ nRG,
    float* __restrict__ dz2G)
{
    __shared__ float smem[14848];   // 59392 B, aliased per role
    __shared__ int nR_s;
    int tid = threadIdx.x, lane = tid & 63, w = tid >> 6;
    const float dv3 = 1.0f/3.0f;

    if (blockIdx.x < FWD2_GEMM_BLOCKS) {
        float* W2T = smem;          // 64 x 132
        float* AHs = smem + 8448;   // 32 x 132
        float* s2  = smem + 12672;  // 32 x 68
        for (int t = tid; t < 128*64; t += 256) {
            int k = t >> 6, c = t & 63;
            W2T[c*132 + k] = W2[t];
        }
        int r0 = blockIdx.x * 32;
        for (int t = tid; t < 32*32; t += 256) {
            int row = t >> 5, q = t & 31;
            *(float4*)&AHs[row*132 + q*4] = *(const float4*)&AH[(size_t)(r0+row)*DH + q*4];
        }
        __syncthreads();
        int tc = tid & 15, tr = tid >> 4;
        float acc[2][4];
        #pragma unroll
        for (int r = 0; r < 2; ++r)
            #pragma unroll
            for (int j = 0; j < 4; ++j) acc[r][j] = 0.f;
        #pragma unroll
        for (int k0 = 0; k0 < 128; k0 += 4) {
            float4 a0 = *(const float4*)&AHs[(tr*2+0)*132 + k0];
            float4 a1 = *(const float4*)&AHs[(tr*2+1)*132 + k0];
            #pragma unroll
            for (int j = 0; j < 4; ++j) {
                float4 wv = *(const float4*)&W2T[(tc + 16*j)*132 + k0];
                acc[0][j] += a0.x*wv.x + a0.y*wv.y + a0.z*wv.z + a0.w*wv.w;
                acc[1][j] += a1.x*wv.x + a1.y*wv.y + a1.z*wv.z + a1.w*wv.w;
            }
        }
        #pragma unroll
        for (int r = 0; r < 2; ++r) {
            int row = tr*2 + r;
            float nv_ = nodeval[r0 + row];
            #pragma unroll
            for (int j = 0; j < 4; ++j) {
                int col = tc + 16*j;
                s2[row*68 + col] = acc[r][j] + nv_*b2[col];
            }
        }
        __syncthreads();
        float gm = gamma[lane], bt = beta[lane];
        for (int rr = 0; rr < 8; ++rr) {
            int row = w*8 + rr;
            int v = r0 + row;
            float xv = s2[row*68 + lane];
            float s = xv;
            for (int o = 32; o > 0; o >>= 1) s += __shfl_xor(s, o);
            float mu = s * (1.f/64.f);
            float d = xv - mu;
            float vs = d*d;
            for (int o = 32; o > 0; o >>= 1) vs += __shfl_xor(vs, o);
            float rstd = 1.0f / sqrtf(vs*(1.f/64.f) + 1e-5f);
            float h = d*rstd*gm + bt;
            outvar[(size_t)v*DO + lane] = xv;
            holo  [(size_t)v*DO + lane] = h;
            out   [(size_t)v*DO + lane] = h;
        }
    } else {
        // ---- corr_a role ----
        float* W2s = smem;                // 128 x 64
        float* dh  = smem + 8192;         // 4 x 128
        float* Rw  = smem + 8704;         // MAXR
        int*   Rn  = (int*)(smem + 8800); // MAXR
        int b = blockIdx.x - FWD2_GEMM_BLOCKS;
        int i = breakidx[b];
        for (int t = tid; t < 128*64; t += 256) W2s[t] = W2[t];
        if (tid < 64) {
            if (i >= NV) {
                int c = i - NV;
                float di = dinvC[c];
                int p0 = csr_off[c], len = csr_off[c+1] - p0;
                if (len <= 64) {
                    int v = (lane < len) ? csr_v[p0 + lane] : 0x7fffffff;
                    int firstLane = 64, mult = 0;
                    for (int m = 0; m < 64; ++m) {
                        int vm = __shfl(v, m);
                        if (vm == v) { mult++; if (m < firstLane) firstLane = m; }
                    }
                    bool head = (lane < len) && (firstLane == lane);
                    unsigned long long hmask = __ballot(head);
                    int hrk = 0;
                    for (int m = 0; m < 64; ++m) {
                        if (!((hmask >> m) & 1)) continue;
                        int vm = __shfl(v, m);
                        if (vm < v) hrk++;
                    }
                    if (head) { Rn[hrk] = v; Rw[hrk] = (float)mult * (dv3 * di); }
                    int nH = __popcll(hmask);
                    if (lane == 0) { Rn[nH] = i; Rw[nH] = di*di; nR_s = nH + 1; }
                } else if (lane == 0) {
                    int n = 0;
                    for (int p = p0; p < p0 + len; ++p) {
                        int v = csr_v[p]; int f = -1;
                        for (int q = 0; q < n; ++q) if (Rn[q] == v) { f = q; break; }
                        if (f >= 0) Rw[f] += dv3 * di;
                        else if (n < MAXR-1) { Rn[n] = v; Rw[n] = dv3 * di; ++n; }
                    }
                    Rn[n] = i; Rw[n] = di*di; nR_s = n + 1;
                }
            } else if (lane == 0) {
                float di = dv3;
                int cn[DEG];
                for (int k = 0; k < DEG; ++k) cn[k] = NV + conArr[i*DEG + k];
                for (int a = 1; a < DEG; ++a) { int key = cn[a]; int bb = a-1;
                    while (bb >= 0 && cn[bb] > key) { cn[bb+1] = cn[bb]; --bb; } cn[bb+1] = key; }
                int n = 0, k = 0;
                while (k < DEG) { int u = cn[k]; int m = 1; ++k;
                    while (k < DEG && cn[k] == u) { ++m; ++k; }
                    Rn[n] = u; Rw[n] = (float)m * dinvC[u - NV] * di; ++n; }
                Rn[n] = i; Rw[n] = di*di; nR_s = n + 1;
            }
        }
        __syncthreads();
        int nR = nR_s;
        for (int t = tid; t < nR; t += 256) { RnG[b*MAXR + t] = Rn[t]; RwG[b*MAXR + t] = Rw[t]; }
        if (tid == 0) nRG[b] = nR;
        for (int r0 = 0; r0 < nR; r0 += 4) {
            __syncthreads();
            for (int t = tid; t < 512; t += 256) {
                int ty = t >> 7, k = t & 127;
                int r = r0 + ty;
                if (r < nR) {
                    float s1 = S1[(size_t)Rn[r]*DH + k];
                    float a = s1 + Rw[r] * W1[64*128 + k];
                    dh[ty*128 + k] = fmaxf(a, 0.f) - fmaxf(s1, 0.f);
                }
            }
            __syncthreads();
            int ty2 = tid >> 6, c2 = tid & 63;
            int r2 = r0 + ty2;
            if (r2 < nR) {
                float accv = 0.f;
                #pragma unroll
                for (int kk = 0; kk < 128; ++kk) accv += dh[ty2*128 + kk] * W2s[kk*64 + c2];
                dz2G[((size_t)b*MAXR + r2)*DO + c2] = accv;
            }
        }
    }
}

// ---------------- corr_b: one block per break; cross-break overlap via atomicAdd ----------------
__global__ __launch_bounds__(256) void k_corr_b(const int* __restrict__ RnG, const float* __restrict__ RwG,
                         const int* __restrict__ nRG, const float* __restrict__ dz2G,
                         const int* __restrict__ breakidx, const float* __restrict__ dinvC,
                         const int* __restrict__ conArr, const int* __restrict__ csr_off,
                         const int* __restrict__ csr_v,
                         const float* __restrict__ outvar, const float* __restrict__ holo,
                         const float* __restrict__ gamma, const float* __restrict__ beta,
                         float* __restrict__ out) {
    int b = blockIdx.x;
    int lane = threadIdx.x & 63, wv = threadIdx.x >> 6; // 4 waves
    const float dv3 = 1.0f/3.0f;
    __shared__ int Jn[MAXJ];
    __shared__ int nJ_s;
    int i = breakidx[b];
    int nR = nRG[b];
    float gm = gamma[lane], bt = beta[lane];
    if (i >= NV) {
        int nJ = nR - 1;
        const float* dzi = &dz2G[((size_t)b*MAXR + (nR-1))*DO];
        for (int j0 = wv; j0 < nJ; j0 += 4) {
            int j = RnG[b*MAXR + j0];
            float aji = RwG[b*MAXR + j0];
            float x = outvar[(size_t)j*DO + lane]
                    + aji * dzi[lane]
                    + dv3*dv3 * dz2G[((size_t)b*MAXR + j0)*DO + lane];
            float s = x; for (int o = 32; o > 0; o >>= 1) s += __shfl_xor(s, o);
            float mu = s * (1.f/64.f);
            float d = x - mu;
            float vs = d*d; for (int o = 32; o > 0; o >>= 1) vs += __shfl_xor(vs, o);
            float rstd = 1.0f / sqrtf(vs*(1.f/64.f) + 1e-5f);
            float hn = d*rstd*gm + bt;
            atomicAdd(&out[(size_t)j*DO + lane], 0.125f * (hn - holo[(size_t)j*DO + lane]));
        }
    } else {
        // variable break node (defensive; analytically never top-k)
        if (threadIdx.x == 0) {
            int n = 0; Jn[n++] = i;
            for (int r = 0; r < nR-1; ++r) {
                int c = RnG[b*MAXR + r] - NV;
                for (int p = csr_off[c]; p < csr_off[c+1]; ++p) {
                    int u = csr_v[p];
                    bool found = false;
                    for (int q = 0; q < n; ++q) if (Jn[q] == u) { found = true; break; }
                    if (!found && n < MAXJ) Jn[n++] = u;
                }
            }
            nJ_s = n;
        }
        __syncthreads();
        int nJ = nJ_s;
        for (int j0 = wv; j0 < nJ; j0 += 4) {
            int j = Jn[j0];
            float x = outvar[(size_t)j*DO + lane];
            for (int k = 0; k < DEG; ++k) {
                int cn = NV + conArr[j*DEG + k];
                for (int r = 0; r < nR-1; ++r)
                    if (RnG[b*MAXR + r] == cn) {
                        x += dv3 * dinvC[cn - NV] * dz2G[((size_t)b*MAXR + r)*DO + lane];
                        break;
                    }
            }
            if (j == i) x += dv3*dv3 * dz2G[((size_t)b*MAXR + nR-1)*DO + lane];
            float s = x; for (int o = 32; o > 0; o >>= 1) s += __shfl_xor(s, o);
            float mu = s * (1.f/64.f);
            float d = x - mu;
            float vs = d*d; for (int o = 32; o > 0; o >>= 1) vs += __shfl_xor(vs, o);
            float rstd = 1.0f / sqrtf(vs*(1.f/64.f) + 1e-5f);
            float hn = d*rstd*gm + bt;
            atomicAdd(&out[(size_t)j*DO + lane], 0.125f * (hn - holo[(size_t)j*DO + lane]));
        }
    }
}

// ---------------- launch ----------------

extern "C" void kernel_launch(void* const* d_in, const int* in_sizes, int n_in,
                              void* d_out, int out_size, void* d_ws, size_t ws_size,
                              hipStream_t stream) {
    const float* vf    = (const float*)d_in[0];
    const float* cf    = (const float*)d_in[1];
    const float* W1    = (const float*)d_in[2];
    const float* b1    = (const float*)d_in[3];
    const float* W2    = (const float*)d_in[4];
    const float* b2    = (const float*)d_in[5];
    const float* gamma = (const float*)d_in[6];
    const float* beta  = (const float*)d_in[7];
    const int*   ei    = (const int*)d_in[8];   // [0..NE) = con, [NE..2NE) = var
    const int*   conArr = ei;
    float* out = (float*)d_out;

    char* ws = (char*)d_ws;
    size_t off = 0;
    auto alloc = [&](size_t bytes) { char* p = ws + off; off = (off + bytes + 255) & ~(size_t)255; return p; };
    float* dinvC   = (float*)alloc(NC*4);
    int*   csr_off = (int*)  alloc((NC+1)*4);
    int*   csr_cur = (int*)  alloc(NC*4);
    int*   csr_v   = (int*)  alloc(NE*4);
    float* nodeval = (float*)alloc(NN*4);
    int*   breakix = (int*)  alloc(NB*4);
    float* AX      = (float*)alloc((size_t)NN*DF*4);
    float* S1      = (float*)alloc((size_t)NN*DH*4);
    float* AH      = (float*)alloc((size_t)NV*DH*4);
    float* outvar  = (float*)alloc((size_t)NV*DO*4);
    float* holo    = (float*)alloc((size_t)NV*DO*4);
    int*   RnG     = (int*)  alloc(NB*MAXR*4);
    float* RwG     = (float*)alloc(NB*MAXR*4);
    int*   nRG     = (int*)  alloc(NB*4);
    float* dz2G    = (float*)alloc((size_t)NB*MAXR*DO*4);

    k_setup <<<G_, 1024, 0, stream>>>(conArr, csr_off, csr_cur, dinvC, nodeval, breakix);
    k_fill  <<<(NE+1023)/1024, 1024, 0, stream>>>(conArr, csr_cur, csr_v);
    k_spmmX <<<NN/4, 256, 0, stream>>>(vf, cf, dinvC, conArr, csr_off, csr_v, AX);
    k_gemm1 <<<NN/32, 256, 0, stream>>>(AX, W1, b1, nodeval, S1);
    k_spmmH <<<NV/2, 256, 0, stream>>>(S1, dinvC, conArr, AH);
    k_fwd2  <<<FWD2_GEMM_BLOCKS + NB, 256, 0, stream>>>(S1, AH, dinvC, conArr, csr_off, csr_v,
                                       W1, W2, b2, nodeval, gamma, beta, breakix,
                                       outvar, holo, out, RnG, RwG, nRG, dz2G);
    k_corr_b<<<NB, 256, 0, stream>>>(RnG, RwG, nRG, dz2G, breakix, dinvC, conArr,
                                     csr_off, csr_v, outvar, holo, gamma, beta, out);
}

// Round 10
// 95.201 us; speedup vs baseline: 1.8329x; 1.1366x over previous
//
#include <hip/hip_runtime.h>
#include <hip/hip_bf16.h>

#define G_      4
#define NVP     3000
#define NCP     1000
#define DEG     8
#define NV      (G_*NVP)      // 12000
#define NC      (G_*NCP)      // 4000
#define NN      (NV+NC)       // 16000
#define NE      (NV*DEG)      // 96000
#define EPG     (NVP*DEG)     // 24000 edges per graph
#define DF      64
#define DH      128
#define DO      64
#define KB      8
#define NB      (G_*KB)       // 32 break nodes
#define MAXR    96
#define MAXJ    640
#define F2_GEMM_BLOCKS (NV/32)   // 375

// ---------------- setup: count/scan/dinv/nodeval/topk (graph-local, 4 blocks) ----------------
__global__ __launch_bounds__(1024) void k_setup(const int* __restrict__ conArr,
    int* __restrict__ csr_off, int* __restrict__ csr_cur,
    float* __restrict__ dinvC_g, float* __restrict__ nodeval, int* __restrict__ breakix)
{
    __shared__ int   cnt[NCP];
    __shared__ float dinvC[NCP];
    __shared__ float nvl[NVP + NCP];
    __shared__ int   wsum[16];
    __shared__ float mv[16]; __shared__ int mp[16];

    int g = blockIdx.x, tid = threadIdx.x, lane = tid & 63, w = tid >> 6;
    int ebase = g * EPG, cb = g * NCP;
    const float dv3 = 1.0f/3.0f;

    if (tid < NCP) cnt[tid] = 0;
    __syncthreads();
    for (int e = tid; e < EPG; e += 1024)
        atomicAdd(&cnt[conArr[ebase + e] - cb], 1);
    __syncthreads();
    int x = (tid < NCP) ? cnt[tid] : 0;
    int orig = x;
    for (int o = 1; o < 64; o <<= 1) { int y = __shfl_up(x, o); if (lane >= o) x += y; }
    if (lane == 63) wsum[w] = x;
    __syncthreads();
    if (tid == 0) { int run = 0; for (int t = 0; t < 16; ++t) { int z = wsum[t]; wsum[t] = run; run += z; } }
    __syncthreads();
    int excl = x - orig + wsum[w];
    if (tid < NCP) {
        csr_off[cb + tid] = ebase + excl;
        csr_cur[cb + tid] = ebase + excl;
        float dc = 1.0f / sqrtf((float)(orig + 1));
        dinvC[tid] = dc;
        dinvC_g[cb + tid] = dc;
        float nvc = (float)orig * (dc * dv3) + dc*dc;
        nvl[NVP + tid] = nvc;
        nodeval[NV + cb + tid] = nvc;
    }
    if (g == 0 && tid == 0) csr_off[NC] = NE;
    __syncthreads();
    for (int v = tid; v < NVP; v += 1024) {
        float s = 0.f;
        int e0 = ebase + v*DEG;
        #pragma unroll
        for (int k = 0; k < DEG; ++k) s += dv3 * dinvC[conArr[e0+k] - cb];
        float val = s + dv3*dv3;
        nvl[v] = val;
        nodeval[g*NVP + v] = val;
    }
    __syncthreads();
    for (int it = 0; it < KB; ++it) {
        float bv = -1e30f; int bp = 1 << 30;
        for (int p = tid; p < NVP+NCP; p += 1024) {
            float vv = nvl[p];
            if (vv > bv || (vv == bv && p < bp)) { bv = vv; bp = p; }
        }
        for (int o = 32; o > 0; o >>= 1) {
            float ov = __shfl_xor(bv, o); int op = __shfl_xor(bp, o);
            if (ov > bv || (ov == bv && op < bp)) { bv = ov; bp = op; }
        }
        if (lane == 0) { mv[w] = bv; mp[w] = bp; }
        __syncthreads();
        if (tid == 0) {
            float fv = mv[0]; int fp = mp[0];
            for (int t = 1; t < 16; ++t)
                if (mv[t] > fv || (mv[t] == fv && mp[t] < fp)) { fv = mv[t]; fp = mp[t]; }
            nvl[fp] = -1e30f;
            breakix[g*KB + it] = (fp < NVP) ? (g*NVP + fp) : (NV + g*NCP + (fp - NVP));
        }
        __syncthreads();
    }
}

// ---------------- fill: chip-wide scattered CSR fill ----------------
__global__ __launch_bounds__(1024) void k_fill(const int* __restrict__ conArr,
                                               int* __restrict__ csr_cur,
                                               int* __restrict__ csr_v) {
    int e = blockIdx.x*1024 + threadIdx.x;
    if (e < NE) { int p = atomicAdd(&csr_cur[conArr[e]], 1); csr_v[p] = e >> 3; }
}

// ---------------- f1: fused spmmX + gemm1 -> S1 (NN x 128); 1 row/wave staging ----------------
__global__ __launch_bounds__(1024) void k_f1(const float* __restrict__ vf, const float* __restrict__ cf,
    const float* __restrict__ dinvC, const int* __restrict__ conArr,
    const int* __restrict__ csr_off, const int* __restrict__ csr_v,
    const float* __restrict__ W1, const float* __restrict__ b1,
    const float* __restrict__ nodeval, float* __restrict__ S1)
{
    __shared__ float W1T[128*68];   // [c][k], padded
    __shared__ float AXs[32*68];
    int tid = threadIdx.x, lane = tid & 63, w = tid >> 6;
    const float dv3 = 1.0f/3.0f;
    for (int t = tid; t < 64*128; t += 1024) {
        int k = t >> 7, c = t & 127;
        W1T[c*68 + k] = W1[t];
    }
    int r0 = blockIdx.x * 32;
    // stage: 16 waves x 2 rows, 1 row at a time per wave (max gather TLP)
    for (int rr = w*2; rr < w*2 + 2; ++rr) {
        int row = r0 + rr;
        float acc, di;
        if (row < NV) {
            di = dv3;
            acc = dv3 * vf[(size_t)row*DF + lane];
            int e0 = row*DEG;
            #pragma unroll
            for (int k = 0; k < DEG; ++k) {
                int c = conArr[e0+k];
                acc += dinvC[c] * cf[(size_t)c*DF + lane];
            }
        } else {
            int c = row - NV;
            di = dinvC[c];
            float base = di * cf[(size_t)c*DF + lane];
            int p0 = csr_off[c], p1 = csr_off[c+1];
            int len = p1 - p0;
            int myv = (p0 + lane < p1) ? csr_v[p0 + lane] : 0;
            int lim = len < 64 ? len : 64;
            float a0 = 0.f, a1 = 0.f, a2 = 0.f, a3 = 0.f;
            int m = 0;
            for (; m + 4 <= lim; m += 4) {
                int v0 = __shfl(myv, m+0);
                int v1 = __shfl(myv, m+1);
                int v2 = __shfl(myv, m+2);
                int v3 = __shfl(myv, m+3);
                a0 += vf[(size_t)v0*DF + lane];
                a1 += vf[(size_t)v1*DF + lane];
                a2 += vf[(size_t)v2*DF + lane];
                a3 += vf[(size_t)v3*DF + lane];
            }
            for (; m < lim; ++m) { int v = __shfl(myv, m); a0 += vf[(size_t)v*DF + lane]; }
            for (int p = p0 + 64; p < p1; ++p) a0 += vf[(size_t)csr_v[p]*DF + lane]; // defensive
            acc = base + dv3 * ((a0 + a1) + (a2 + a3));
        }
        AXs[rr*68 + lane] = di * acc;
    }
    __syncthreads();
    // GEMM: thread -> 1 row x 4 cols (32 rows x 128 cols = 4096 outputs = 1024 thr x 4)
    int tc = tid & 15, tr = tid >> 4;    // tr 0..63
    int row = tr & 31, chh = tr >> 5;    // chh 0/1 -> col offset 0/64
    float a4[4] = {0.f, 0.f, 0.f, 0.f};
    #pragma unroll
    for (int k0 = 0; k0 < 64; k0 += 4) {
        float4 a = *(const float4*)&AXs[row*68 + k0];
        #pragma unroll
        for (int j = 0; j < 4; ++j) {
            float4 wv = *(const float4*)&W1T[(tc + 16*j + 64*chh)*68 + k0];
            a4[j] += a.x*wv.x + a.y*wv.y + a.z*wv.z + a.w*wv.w;
        }
    }
    float nv_ = nodeval[r0 + row];
    #pragma unroll
    for (int j = 0; j < 4; ++j) {
        int col = tc + 16*j + 64*chh;
        S1[(size_t)(r0 + row)*DH + col] = a4[j] + nv_*b1[col];
    }
}

// ---------------- f2: blocks [0,375) fused spmmH+gemm2+LN; blocks [375,407) corr_a ----------------
__global__ __launch_bounds__(1024) void k_f2(const float* __restrict__ S1,
    const float* __restrict__ dinvC, const int* __restrict__ conArr,
    const int* __restrict__ csr_off, const int* __restrict__ csr_v,
    const float* __restrict__ W1, const float* __restrict__ W2,
    const float* __restrict__ b2, const float* __restrict__ nodeval,
    const float* __restrict__ gamma, const float* __restrict__ beta,
    const int* __restrict__ breakidx,
    float* __restrict__ outvar, float* __restrict__ holo, float* __restrict__ out,
    int* __restrict__ RnG, float* __restrict__ RwG, int* __restrict__ nRG,
    float* __restrict__ dz2G)
{
    __shared__ float smem[14848];   // 59392 B, aliased per role
    __shared__ int nR_s;
    int tid = threadIdx.x, lane = tid & 63, w = tid >> 6;
    const float dv3 = 1.0f/3.0f;

    if (blockIdx.x < F2_GEMM_BLOCKS) {
        float* W2T = smem;          // 64 x 132
        float* AHs = smem + 8448;   // 32 x 132
        float* s2  = smem + 12672;  // 32 x 68
        for (int t = tid; t < 128*64; t += 1024) {
            int k = t >> 6, c = t & 63;
            W2T[c*132 + k] = W2[t];
        }
        int r0 = blockIdx.x * 32;
        // stage: 16 waves x 2 rows, gather A_hat @ relu(S1)
        for (int rr = w*2; rr < w*2 + 2; ++rr) {
            int v = r0 + rr;
            float a0 = dv3 * fmaxf(S1[(size_t)v*DH + lane], 0.f);
            float a1 = dv3 * fmaxf(S1[(size_t)v*DH + 64 + lane], 0.f);
            int e0 = v*DEG;
            #pragma unroll
            for (int k = 0; k < DEG; ++k) {
                int c = conArr[e0+k];
                float dc = dinvC[c];
                a0 += dc * fmaxf(S1[(size_t)(NV+c)*DH + lane], 0.f);
                a1 += dc * fmaxf(S1[(size_t)(NV+c)*DH + 64 + lane], 0.f);
            }
            AHs[rr*132 + lane]      = dv3 * a0;
            AHs[rr*132 + 64 + lane] = dv3 * a1;
        }
        __syncthreads();
        // GEMM: thread -> 1 row x 2 cols (32 x 64 = 2048 outputs)
        int tc = tid & 15, tr = tid >> 4;   // 0..63
        int row = tr & 31, jh = tr >> 5;    // jh 0/1
        float a2[2] = {0.f, 0.f};
        #pragma unroll
        for (int k0 = 0; k0 < 128; k0 += 4) {
            float4 a = *(const float4*)&AHs[row*132 + k0];
            #pragma unroll
            for (int j = 0; j < 2; ++j) {
                float4 wv = *(const float4*)&W2T[(tc + 16*(j + 2*jh))*132 + k0];
                a2[j] += a.x*wv.x + a.y*wv.y + a.z*wv.z + a.w*wv.w;
            }
        }
        float nv_ = nodeval[r0 + row];
        #pragma unroll
        for (int j = 0; j < 2; ++j) {
            int col = tc + 16*(j + 2*jh);
            s2[row*68 + col] = a2[j] + nv_*b2[col];
        }
        __syncthreads();
        // LN: 16 waves x 2 rows
        float gm = gamma[lane], bt = beta[lane];
        for (int rr = w*2; rr < w*2 + 2; ++rr) {
            int v = r0 + rr;
            float xv = s2[rr*68 + lane];
            float s = xv;
            for (int o = 32; o > 0; o >>= 1) s += __shfl_xor(s, o);
            float mu = s * (1.f/64.f);
            float d = xv - mu;
            float vs = d*d;
            for (int o = 32; o > 0; o >>= 1) vs += __shfl_xor(vs, o);
            float rstd = 1.0f / sqrtf(vs*(1.f/64.f) + 1e-5f);
            float h = d*rstd*gm + bt;
            outvar[(size_t)v*DO + lane] = xv;
            holo  [(size_t)v*DO + lane] = h;
            out   [(size_t)v*DO + lane] = h;
        }
    } else {
        // ---- corr_a role ----
        float* W2s = smem;                // 128 x 64 = 8192
        float* dh  = smem + 8192;         // 8 x 128 = 1024
        float* Rw  = smem + 9216;         // MAXR
        int*   Rn  = (int*)(smem + 9312); // MAXR
        int b = blockIdx.x - F2_GEMM_BLOCKS;
        int i = breakidx[b];
        for (int t = tid; t < 128*64; t += 1024) W2s[t] = W2[t];
        if (tid < 64) {
            if (i >= NV) {
                int c = i - NV;
                float di = dinvC[c];
                int p0 = csr_off[c], len = csr_off[c+1] - p0;
                if (len <= 64) {
                    int v = (lane < len) ? csr_v[p0 + lane] : 0x7fffffff;
                    int firstLane = 64, mult = 0;
                    for (int m = 0; m < 64; ++m) {
                        int vm = __shfl(v, m);
                        if (vm == v) { mult++; if (m < firstLane) firstLane = m; }
                    }
                    bool head = (lane < len) && (firstLane == lane);
                    unsigned long long hmask = __ballot(head);
                    int hrk = 0;
                    for (int m = 0; m < 64; ++m) {
                        if (!((hmask >> m) & 1)) continue;
                        int vm = __shfl(v, m);
                        if (vm < v) hrk++;
                    }
                    if (head) { Rn[hrk] = v; Rw[hrk] = (float)mult * (dv3 * di); }
                    int nH = __popcll(hmask);
                    if (lane == 0) { Rn[nH] = i; Rw[nH] = di*di; nR_s = nH + 1; }
                } else if (lane == 0) {
                    int n = 0;
                    for (int p = p0; p < p0 + len; ++p) {
                        int v = csr_v[p]; int f = -1;
                        for (int q = 0; q < n; ++q) if (Rn[q] == v) { f = q; break; }
                        if (f >= 0) Rw[f] += dv3 * di;
                        else if (n < MAXR-1) { Rn[n] = v; Rw[n] = dv3 * di; ++n; }
                    }
                    Rn[n] = i; Rw[n] = di*di; nR_s = n + 1;
                }
            } else if (lane == 0) {
                float di = dv3;
                int cn[DEG];
                for (int k = 0; k < DEG; ++k) cn[k] = NV + conArr[i*DEG + k];
                for (int a = 1; a < DEG; ++a) { int key = cn[a]; int bb = a-1;
                    while (bb >= 0 && cn[bb] > key) { cn[bb+1] = cn[bb]; --bb; } cn[bb+1] = key; }
                int n = 0, k = 0;
                while (k < DEG) { int u = cn[k]; int m = 1; ++k;
                    while (k < DEG && cn[k] == u) { ++m; ++k; }
                    Rn[n] = u; Rw[n] = (float)m * dinvC[u - NV] * di; ++n; }
                Rn[n] = i; Rw[n] = di*di; nR_s = n + 1;
            }
        }
        __syncthreads();
        int nR = nR_s;
        for (int t = tid; t < nR; t += 1024) { RnG[b*MAXR + t] = Rn[t]; RwG[b*MAXR + t] = Rw[t]; }
        if (tid == 0) nRG[b] = nR;
        for (int r0c = 0; r0c < nR; r0c += 8) {
            __syncthreads();
            {
                int ty = tid >> 7, k = tid & 127;   // 8 x 128 = 1024
                int r = r0c + ty;
                if (r < nR) {
                    float s1 = S1[(size_t)Rn[r]*DH + k];
                    float a = s1 + Rw[r] * W1[64*128 + k];
                    dh[ty*128 + k] = fmaxf(a, 0.f) - fmaxf(s1, 0.f);
                }
            }
            __syncthreads();
            int ty2 = tid >> 6, c2 = tid & 63;      // 16 groups; use first 8
            if (ty2 < 8) {
                int r2 = r0c + ty2;
                if (r2 < nR) {
                    float accv = 0.f;
                    #pragma unroll
                    for (int kk = 0; kk < 128; ++kk) accv += dh[ty2*128 + kk] * W2s[kk*64 + c2];
                    dz2G[((size_t)b*MAXR + r2)*DO + c2] = accv;
                }
            }
        }
    }
}

// ---------------- corr_b: one block per break; cross-break overlap via atomicAdd ----------------
__global__ __launch_bounds__(256) void k_corr_b(const int* __restrict__ RnG, const float* __restrict__ RwG,
                         const int* __restrict__ nRG, const float* __restrict__ dz2G,
                         const int* __restrict__ breakidx, const float* __restrict__ dinvC,
                         const int* __restrict__ conArr, const int* __restrict__ csr_off,
                         const int* __restrict__ csr_v,
                         const float* __restrict__ outvar, const float* __restrict__ holo,
                         const float* __restrict__ gamma, const float* __restrict__ beta,
                         float* __restrict__ out) {
    int b = blockIdx.x;
    int lane = threadIdx.x & 63, wv = threadIdx.x >> 6; // 4 waves
    const float dv3 = 1.0f/3.0f;
    __shared__ int Jn[MAXJ];
    __shared__ int nJ_s;
    int i = breakidx[b];
    int nR = nRG[b];
    float gm = gamma[lane], bt = beta[lane];
    if (i >= NV) {
        int nJ = nR - 1;
        const float* dzi = &dz2G[((size_t)b*MAXR + (nR-1))*DO];
        for (int j0 = wv; j0 < nJ; j0 += 4) {
            int j = RnG[b*MAXR + j0];
            float aji = RwG[b*MAXR + j0];
            float x = outvar[(size_t)j*DO + lane]
                    + aji * dzi[lane]
                    + dv3*dv3 * dz2G[((size_t)b*MAXR + j0)*DO + lane];
            float s = x; for (int o = 32; o > 0; o >>= 1) s += __shfl_xor(s, o);
            float mu = s * (1.f/64.f);
            float d = x - mu;
            float vs = d*d; for (int o = 32; o > 0; o >>= 1) vs += __shfl_xor(vs, o);
            float rstd = 1.0f / sqrtf(vs*(1.f/64.f) + 1e-5f);
            float hn = d*rstd*gm + bt;
            atomicAdd(&out[(size_t)j*DO + lane], 0.125f * (hn - holo[(size_t)j*DO + lane]));
        }
    } else {
        // variable break node (defensive; analytically never top-k)
        if (threadIdx.x == 0) {
            int n = 0; Jn[n++] = i;
            for (int r = 0; r < nR-1; ++r) {
                int c = RnG[b*MAXR + r] - NV;
                for (int p = csr_off[c]; p < csr_off[c+1]; ++p) {
                    int u = csr_v[p];
                    bool found = false;
                    for (int q = 0; q < n; ++q) if (Jn[q] == u) { found = true; break; }
                    if (!found && n < MAXJ) Jn[n++] = u;
                }
            }
            nJ_s = n;
        }
        __syncthreads();
        int nJ = nJ_s;
        for (int j0 = wv; j0 < nJ; j0 += 4) {
            int j = Jn[j0];
            float x = outvar[(size_t)j*DO + lane];
            for (int k = 0; k < DEG; ++k) {
                int cn = NV + conArr[j*DEG + k];
                for (int r = 0; r < nR-1; ++r)
                    if (RnG[b*MAXR + r] == cn) {
                        x += dv3 * dinvC[cn - NV] * dz2G[((size_t)b*MAXR + r)*DO + lane];
                        break;
                    }
            }
            if (j == i) x += dv3*dv3 * dz2G[((size_t)b*MAXR + nR-1)*DO + lane];
            float s = x; for (int o = 32; o > 0; o >>= 1) s += __shfl_xor(s, o);
            float mu = s * (1.f/64.f);
            float d = x - mu;
            float vs = d*d; for (int o = 32; o > 0; o >>= 1) vs += __shfl_xor(vs, o);
            float rstd = 1.0f / sqrtf(vs*(1.f/64.f) + 1e-5f);
            float hn = d*rstd*gm + bt;
            atomicAdd(&out[(size_t)j*DO + lane], 0.125f * (hn - holo[(size_t)j*DO + lane]));
        }
    }
}

// ---------------- launch ----------------

extern "C" void kernel_launch(void* const* d_in, const int* in_sizes, int n_in,
                              void* d_out, int out_size, void* d_ws, size_t ws_size,
                              hipStream_t stream) {
    const float* vf    = (const float*)d_in[0];
    const float* cf    = (const float*)d_in[1];
    const float* W1    = (const float*)d_in[2];
    const float* b1    = (const float*)d_in[3];
    const float* W2    = (const float*)d_in[4];
    const float* b2    = (const float*)d_in[5];
    const float* gamma = (const float*)d_in[6];
    const float* beta  = (const float*)d_in[7];
    const int*   ei    = (const int*)d_in[8];   // [0..NE) = con, [NE..2NE) = var
    const int*   conArr = ei;
    float* out = (float*)d_out;

    char* ws = (char*)d_ws;
    size_t off = 0;
    auto alloc = [&](size_t bytes) { char* p = ws + off; off = (off + bytes + 255) & ~(size_t)255; return p; };
    float* dinvC   = (float*)alloc(NC*4);
    int*   csr_off = (int*)  alloc((NC+1)*4);
    int*   csr_cur = (int*)  alloc(NC*4);
    int*   csr_v   = (int*)  alloc(NE*4);
    float* nodeval = (float*)alloc(NN*4);
    int*   breakix = (int*)  alloc(NB*4);
    float* S1      = (float*)alloc((size_t)NN*DH*4);
    float* outvar  = (float*)alloc((size_t)NV*DO*4);
    float* holo    = (float*)alloc((size_t)NV*DO*4);
    int*   RnG     = (int*)  alloc(NB*MAXR*4);
    float* RwG     = (float*)alloc(NB*MAXR*4);
    int*   nRG     = (int*)  alloc(NB*4);
    float* dz2G    = (float*)alloc((size_t)NB*MAXR*DO*4);

    k_setup <<<G_, 1024, 0, stream>>>(conArr, csr_off, csr_cur, dinvC, nodeval, breakix);
    k_fill  <<<(NE+1023)/1024, 1024, 0, stream>>>(conArr, csr_cur, csr_v);
    k_f1    <<<NN/32, 1024, 0, stream>>>(vf, cf, dinvC, conArr, csr_off, csr_v, W1, b1, nodeval, S1);
    k_f2    <<<F2_GEMM_BLOCKS + NB, 1024, 0, stream>>>(S1, dinvC, conArr, csr_off, csr_v,
                                       W1, W2, b2, nodeval, gamma, beta, breakix,
                                       outvar, holo, out, RnG, RwG, nRG, dz2G);
    k_corr_b<<<NB, 256, 0, stream>>>(RnG, RwG, nRG, dz2G, breakix, dinvC, conArr,
                                     csr_off, csr_v, outvar, holo, gamma, beta, out);
}

// Round 11
// 94.463 us; speedup vs baseline: 1.8472x; 1.0078x over previous
//
#include <hip/hip_runtime.h>
#include <hip/hip_cooperative_groups.h>
#include <hip/hip_bf16.h>

namespace cg = cooperative_groups;

#define G_      4
#define NVP     3000
#define NCP     1000
#define DEG     8
#define NV      (G_*NVP)      // 12000
#define NC      (G_*NCP)      // 4000
#define NN      (NV+NC)       // 16000
#define NE      (NV*DEG)      // 96000
#define EPG     (NVP*DEG)     // 24000
#define DF      64
#define DH      128
#define DO      64
#define KB      8
#define NB      (G_*KB)       // 32
#define MAXR    96
#define MAXJ    640
#define F2_GEMM_TILES (NV/32)         // 375
#define F1_TILES (NN/32)              // 500
#define F2_TILES (F2_GEMM_TILES+NB)   // 407
#define MEGA_GRID 256

// ================= phase bodies (R10-proven code, tile-parameterized) =================

__device__ __forceinline__ void setup_body(int g, const int* __restrict__ conArr,
    int* __restrict__ csr_off, int* __restrict__ csr_cur,
    float* __restrict__ dinvC_g, float* __restrict__ nodeval, int* __restrict__ breakix,
    float* smemf)
{
    int*   cnt   = (int*)smemf;                  // NCP
    float* dinvC = (float*)(cnt + NCP);          // NCP
    float* nvl   = dinvC + NCP;                  // NVP+NCP
    int*   wsum  = (int*)(nvl + (NVP + NCP));    // 16
    float* mv    = (float*)(wsum + 16);          // 16
    int*   mp    = (int*)(mv + 16);              // 16
    int tid = threadIdx.x, lane = tid & 63, w = tid >> 6;
    int ebase = g * EPG, cb = g * NCP;
    const float dv3 = 1.0f/3.0f;

    if (tid < NCP) cnt[tid] = 0;
    __syncthreads();
    for (int e = tid; e < EPG; e += 1024)
        atomicAdd(&cnt[conArr[ebase + e] - cb], 1);
    __syncthreads();
    int x = (tid < NCP) ? cnt[tid] : 0;
    int orig = x;
    for (int o = 1; o < 64; o <<= 1) { int y = __shfl_up(x, o); if (lane >= o) x += y; }
    if (lane == 63) wsum[w] = x;
    __syncthreads();
    if (tid == 0) { int run = 0; for (int t = 0; t < 16; ++t) { int z = wsum[t]; wsum[t] = run; run += z; } }
    __syncthreads();
    int excl = x - orig + wsum[w];
    if (tid < NCP) {
        csr_off[cb + tid] = ebase + excl;
        csr_cur[cb + tid] = ebase + excl;
        float dc = 1.0f / sqrtf((float)(orig + 1));
        dinvC[tid] = dc;
        dinvC_g[cb + tid] = dc;
        float nvc = (float)orig * (dc * dv3) + dc*dc;
        nvl[NVP + tid] = nvc;
        nodeval[NV + cb + tid] = nvc;
    }
    if (g == 0 && tid == 0) csr_off[NC] = NE;
    __syncthreads();
    for (int v = tid; v < NVP; v += 1024) {
        float s = 0.f;
        int e0 = ebase + v*DEG;
        #pragma unroll
        for (int k = 0; k < DEG; ++k) s += dv3 * dinvC[conArr[e0+k] - cb];
        float val = s + dv3*dv3;
        nvl[v] = val;
        nodeval[g*NVP + v] = val;
    }
    __syncthreads();
    for (int it = 0; it < KB; ++it) {
        float bv = -1e30f; int bp = 1 << 30;
        for (int p = tid; p < NVP+NCP; p += 1024) {
            float vv = nvl[p];
            if (vv > bv || (vv == bv && p < bp)) { bv = vv; bp = p; }
        }
        for (int o = 32; o > 0; o >>= 1) {
            float ov = __shfl_xor(bv, o); int op = __shfl_xor(bp, o);
            if (ov > bv || (ov == bv && op < bp)) { bv = ov; bp = op; }
        }
        if (lane == 0) { mv[w] = bv; mp[w] = bp; }
        __syncthreads();
        if (tid == 0) {
            float fv = mv[0]; int fp = mp[0];
            for (int t = 1; t < 16; ++t)
                if (mv[t] > fv || (mv[t] == fv && mp[t] < fp)) { fv = mv[t]; fp = mp[t]; }
            nvl[fp] = -1e30f;
            breakix[g*KB + it] = (fp < NVP) ? (g*NVP + fp) : (NV + g*NCP + (fp - NVP));
        }
        __syncthreads();
    }
}

__device__ __forceinline__ void f1_body(int tile, bool first,
    const float* __restrict__ vf, const float* __restrict__ cf,
    const float* __restrict__ dinvC, const int* __restrict__ conArr,
    const int* __restrict__ csr_off, const int* __restrict__ csr_v,
    const float* __restrict__ W1, const float* __restrict__ b1,
    const float* __restrict__ nodeval, float* __restrict__ S1, float* smemf)
{
    float* W1T = smemf;            // 128*68
    float* AXs = smemf + 8704;     // 32*68
    int tid = threadIdx.x, lane = tid & 63, w = tid >> 6;
    const float dv3 = 1.0f/3.0f;
    if (!first) __syncthreads();   // protect AXs/W1T from prior-call readers
    if (first) {
        for (int t = tid; t < 64*128; t += 1024) {
            int k = t >> 7, c = t & 127;
            W1T[c*68 + k] = W1[t];
        }
    }
    int r0 = tile * 32;
    for (int rr = w*2; rr < w*2 + 2; ++rr) {
        int row = r0 + rr;
        float acc, di;
        if (row < NV) {
            di = dv3;
            acc = dv3 * vf[(size_t)row*DF + lane];
            int e0 = row*DEG;
            #pragma unroll
            for (int k = 0; k < DEG; ++k) {
                int c = conArr[e0+k];
                acc += dinvC[c] * cf[(size_t)c*DF + lane];
            }
        } else {
            int c = row - NV;
            di = dinvC[c];
            float base = di * cf[(size_t)c*DF + lane];
            int p0 = csr_off[c], p1 = csr_off[c+1];
            int len = p1 - p0;
            int myv = (p0 + lane < p1) ? csr_v[p0 + lane] : 0;
            int lim = len < 64 ? len : 64;
            float a0 = 0.f, a1 = 0.f, a2 = 0.f, a3 = 0.f;
            int m = 0;
            for (; m + 4 <= lim; m += 4) {
                int v0 = __shfl(myv, m+0);
                int v1 = __shfl(myv, m+1);
                int v2 = __shfl(myv, m+2);
                int v3 = __shfl(myv, m+3);
                a0 += vf[(size_t)v0*DF + lane];
                a1 += vf[(size_t)v1*DF + lane];
                a2 += vf[(size_t)v2*DF + lane];
                a3 += vf[(size_t)v3*DF + lane];
            }
            for (; m < lim; ++m) { int v = __shfl(myv, m); a0 += vf[(size_t)v*DF + lane]; }
            for (int p = p0 + 64; p < p1; ++p) a0 += vf[(size_t)csr_v[p]*DF + lane];
            acc = base + dv3 * ((a0 + a1) + (a2 + a3));
        }
        AXs[rr*68 + lane] = di * acc;
    }
    __syncthreads();
    int tc = tid & 15, tr = tid >> 4;
    int row = tr & 31, chh = tr >> 5;
    float a4[4] = {0.f, 0.f, 0.f, 0.f};
    #pragma unroll
    for (int k0 = 0; k0 < 64; k0 += 4) {
        float4 a = *(const float4*)&AXs[row*68 + k0];
        #pragma unroll
        for (int j = 0; j < 4; ++j) {
            float4 wv = *(const float4*)&W1T[(tc + 16*j + 64*chh)*68 + k0];
            a4[j] += a.x*wv.x + a.y*wv.y + a.z*wv.z + a.w*wv.w;
        }
    }
    float nv_ = nodeval[r0 + row];
    #pragma unroll
    for (int j = 0; j < 4; ++j) {
        int col = tc + 16*j + 64*chh;
        S1[(size_t)(r0 + row)*DH + col] = a4[j] + nv_*b1[col];
    }
}

__device__ __forceinline__ void f2gemm_body(int tile, bool first,
    const float* __restrict__ S1, const float* __restrict__ dinvC,
    const int* __restrict__ conArr, const float* __restrict__ W2,
    const float* __restrict__ b2, const float* __restrict__ nodeval,
    const float* __restrict__ gamma, const float* __restrict__ beta,
    float* __restrict__ outvar, float* __restrict__ holo, float* __restrict__ out,
    float* smemf)
{
    float* W2T = smemf;          // 64 x 132
    float* AHs = smemf + 8448;   // 32 x 132
    float* s2  = smemf + 12672;  // 32 x 68
    int tid = threadIdx.x, lane = tid & 63, w = tid >> 6;
    const float dv3 = 1.0f/3.0f;
    if (!first) __syncthreads();
    if (first) {
        for (int t = tid; t < 128*64; t += 1024) {
            int k = t >> 6, c = t & 63;
            W2T[c*132 + k] = W2[t];
        }
    }
    int r0 = tile * 32;
    for (int rr = w*2; rr < w*2 + 2; ++rr) {
        int v = r0 + rr;
        float a0 = dv3 * fmaxf(S1[(size_t)v*DH + lane], 0.f);
        float a1 = dv3 * fmaxf(S1[(size_t)v*DH + 64 + lane], 0.f);
        int e0 = v*DEG;
        #pragma unroll
        for (int k = 0; k < DEG; ++k) {
            int c = conArr[e0+k];
            float dc = dinvC[c];
            a0 += dc * fmaxf(S1[(size_t)(NV+c)*DH + lane], 0.f);
            a1 += dc * fmaxf(S1[(size_t)(NV+c)*DH + 64 + lane], 0.f);
        }
        AHs[rr*132 + lane]      = dv3 * a0;
        AHs[rr*132 + 64 + lane] = dv3 * a1;
    }
    __syncthreads();
    int tc = tid & 15, tr = tid >> 4;
    int row = tr & 31, jh = tr >> 5;
    float a2[2] = {0.f, 0.f};
    #pragma unroll
    for (int k0 = 0; k0 < 128; k0 += 4) {
        float4 a = *(const float4*)&AHs[row*132 + k0];
        #pragma unroll
        for (int j = 0; j < 2; ++j) {
            float4 wv = *(const float4*)&W2T[(tc + 16*(j + 2*jh))*132 + k0];
            a2[j] += a.x*wv.x + a.y*wv.y + a.z*wv.z + a.w*wv.w;
        }
    }
    float nv_ = nodeval[r0 + row];
    #pragma unroll
    for (int j = 0; j < 2; ++j) {
        int col = tc + 16*(j + 2*jh);
        s2[row*68 + col] = a2[j] + nv_*b2[col];
    }
    __syncthreads();
    float gm = gamma[lane], bt = beta[lane];
    for (int rr = w*2; rr < w*2 + 2; ++rr) {
        int v = r0 + rr;
        float xv = s2[rr*68 + lane];
        float s = xv;
        for (int o = 32; o > 0; o >>= 1) s += __shfl_xor(s, o);
        float mu = s * (1.f/64.f);
        float d = xv - mu;
        float vs = d*d;
        for (int o = 32; o > 0; o >>= 1) vs += __shfl_xor(vs, o);
        float rstd = 1.0f / sqrtf(vs*(1.f/64.f) + 1e-5f);
        float h = d*rstd*gm + bt;
        outvar[(size_t)v*DO + lane] = xv;
        holo  [(size_t)v*DO + lane] = h;
        out   [(size_t)v*DO + lane] = h;
    }
}

__device__ __forceinline__ void corra_body(int b,
    const float* __restrict__ S1, const float* __restrict__ dinvC,
    const int* __restrict__ conArr, const int* __restrict__ csr_off,
    const int* __restrict__ csr_v, const float* __restrict__ W1,
    const float* __restrict__ W2, const int* __restrict__ breakidx,
    int* __restrict__ RnG, float* __restrict__ RwG, int* __restrict__ nRG,
    float* __restrict__ dz2G, float* smemf, int& nR_s)
{
    float* W2s = smemf;                 // 128*64
    float* dh  = smemf + 8192;          // 8*128
    float* Rw  = smemf + 9216;          // MAXR
    int*   Rn  = (int*)(smemf + 9312);  // MAXR
    int tid = threadIdx.x, lane = tid & 63;
    const float dv3 = 1.0f/3.0f;
    __syncthreads();                    // protect smem from prior-role readers
    int i = breakidx[b];
    for (int t = tid; t < 128*64; t += 1024) W2s[t] = W2[t];
    if (tid < 64) {
        if (i >= NV) {
            int c = i - NV;
            float di = dinvC[c];
            int p0 = csr_off[c], len = csr_off[c+1] - p0;
            if (len <= 64) {
                int v = (lane < len) ? csr_v[p0 + lane] : 0x7fffffff;
                int firstLane = 64, mult = 0;
                for (int m = 0; m < 64; ++m) {
                    int vm = __shfl(v, m);
                    if (vm == v) { mult++; if (m < firstLane) firstLane = m; }
                }
                bool head = (lane < len) && (firstLane == lane);
                unsigned long long hmask = __ballot(head);
                int hrk = 0;
                for (int m = 0; m < 64; ++m) {
                    if (!((hmask >> m) & 1)) continue;
                    int vm = __shfl(v, m);
                    if (vm < v) hrk++;
                }
                if (head) { Rn[hrk] = v; Rw[hrk] = (float)mult * (dv3 * di); }
                int nH = __popcll(hmask);
                if (lane == 0) { Rn[nH] = i; Rw[nH] = di*di; nR_s = nH + 1; }
            } else if (lane == 0) {
                int n = 0;
                for (int p = p0; p < p0 + len; ++p) {
                    int v = csr_v[p]; int f = -1;
                    for (int q = 0; q < n; ++q) if (Rn[q] == v) { f = q; break; }
                    if (f >= 0) Rw[f] += dv3 * di;
                    else if (n < MAXR-1) { Rn[n] = v; Rw[n] = dv3 * di; ++n; }
                }
                Rn[n] = i; Rw[n] = di*di; nR_s = n + 1;
            }
        } else if (lane == 0) {
            float di = dv3;
            int cn[DEG];
            for (int k = 0; k < DEG; ++k) cn[k] = NV + conArr[i*DEG + k];
            for (int a = 1; a < DEG; ++a) { int key = cn[a]; int bb = a-1;
                while (bb >= 0 && cn[bb] > key) { cn[bb+1] = cn[bb]; --bb; } cn[bb+1] = key; }
            int n = 0, k = 0;
            while (k < DEG) { int u = cn[k]; int m = 1; ++k;
                while (k < DEG && cn[k] == u) { ++m; ++k; }
                Rn[n] = u; Rw[n] = (float)m * dinvC[u - NV] * di; ++n; }
            Rn[n] = i; Rw[n] = di*di; nR_s = n + 1;
        }
    }
    __syncthreads();
    int nR = nR_s;
    for (int t = tid; t < nR; t += 1024) { RnG[b*MAXR + t] = Rn[t]; RwG[b*MAXR + t] = Rw[t]; }
    if (tid == 0) nRG[b] = nR;
    for (int r0c = 0; r0c < nR; r0c += 8) {
        __syncthreads();
        {
            int ty = tid >> 7, k = tid & 127;
            int r = r0c + ty;
            if (r < nR) {
                float s1 = S1[(size_t)Rn[r]*DH + k];
                float a = s1 + Rw[r] * W1[64*128 + k];
                dh[ty*128 + k] = fmaxf(a, 0.f) - fmaxf(s1, 0.f);
            }
        }
        __syncthreads();
        int ty2 = tid >> 6, c2 = tid & 63;
        if (ty2 < 8) {
            int r2 = r0c + ty2;
            if (r2 < nR) {
                float accv = 0.f;
                #pragma unroll
                for (int kk = 0; kk < 128; ++kk) accv += dh[ty2*128 + kk] * W2s[kk*64 + c2];
                dz2G[((size_t)b*MAXR + r2)*DO + c2] = accv;
            }
        }
    }
    __syncthreads();
}

__device__ __forceinline__ void corrb_body(int b,
    const int* __restrict__ RnG, const float* __restrict__ RwG,
    const int* __restrict__ nRG, const float* __restrict__ dz2G,
    const int* __restrict__ breakidx, const float* __restrict__ dinvC,
    const int* __restrict__ conArr, const int* __restrict__ csr_off,
    const int* __restrict__ csr_v,
    const float* __restrict__ outvar, const float* __restrict__ holo,
    const float* __restrict__ gamma, const float* __restrict__ beta,
    float* __restrict__ out, float* smemf)
{
    int* Jn = (int*)smemf;              // MAXJ
    __shared__ int nJ_s;
    int lane = threadIdx.x & 63, wv = threadIdx.x >> 6; // 16 waves
    const float dv3 = 1.0f/3.0f;
    int i = breakidx[b];
    int nR = nRG[b];
    float gm = gamma[lane], bt = beta[lane];
    if (i >= NV) {
        int nJ = nR - 1;
        const float* dzi = &dz2G[((size_t)b*MAXR + (nR-1))*DO];
        for (int j0 = wv; j0 < nJ; j0 += 16) {
            int j = RnG[b*MAXR + j0];
            float aji = RwG[b*MAXR + j0];
            float x = outvar[(size_t)j*DO + lane]
                    + aji * dzi[lane]
                    + dv3*dv3 * dz2G[((size_t)b*MAXR + j0)*DO + lane];
            float s = x; for (int o = 32; o > 0; o >>= 1) s += __shfl_xor(s, o);
            float mu = s * (1.f/64.f);
            float d = x - mu;
            float vs = d*d; for (int o = 32; o > 0; o >>= 1) vs += __shfl_xor(vs, o);
            float rstd = 1.0f / sqrtf(vs*(1.f/64.f) + 1e-5f);
            float hn = d*rstd*gm + bt;
            atomicAdd(&out[(size_t)j*DO + lane], 0.125f * (hn - holo[(size_t)j*DO + lane]));
        }
    } else {
        if (threadIdx.x == 0) {
            int n = 0; Jn[n++] = i;
            for (int r = 0; r < nR-1; ++r) {
                int c = RnG[b*MAXR + r] - NV;
                for (int p = csr_off[c]; p < csr_off[c+1]; ++p) {
                    int u = csr_v[p];
                    bool found = false;
                    for (int q = 0; q < n; ++q) if (Jn[q] == u) { found = true; break; }
                    if (!found && n < MAXJ) Jn[n++] = u;
                }
            }
            nJ_s = n;
        }
        __syncthreads();
        int nJ = nJ_s;
        for (int j0 = wv; j0 < nJ; j0 += 16) {
            int j = Jn[j0];
            float x = outvar[(size_t)j*DO + lane];
            for (int k = 0; k < DEG; ++k) {
                int cn = NV + conArr[j*DEG + k];
                for (int r = 0; r < nR-1; ++r)
                    if (RnG[b*MAXR + r] == cn) {
                        x += dv3 * dinvC[cn - NV] * dz2G[((size_t)b*MAXR + r)*DO + lane];
                        break;
                    }
            }
            if (j == i) x += dv3*dv3 * dz2G[((size_t)b*MAXR + nR-1)*DO + lane];
            float s = x; for (int o = 32; o > 0; o >>= 1) s += __shfl_xor(s, o);
            float mu = s * (1.f/64.f);
            float d = x - mu;
            float vs = d*d; for (int o = 32; o > 0; o >>= 1) vs += __shfl_xor(vs, o);
            float rstd = 1.0f / sqrtf(vs*(1.f/64.f) + 1e-5f);
            float hn = d*rstd*gm + bt;
            atomicAdd(&out[(size_t)j*DO + lane], 0.125f * (hn - holo[(size_t)j*DO + lane]));
        }
    }
}

// ================= mega kernel: phase<0 => cooperative all-phase; else single phase =================

__global__ __launch_bounds__(1024) void k_mega(
    const float* __restrict__ vf, const float* __restrict__ cf,
    const float* __restrict__ W1, const float* __restrict__ b1,
    const float* __restrict__ W2, const float* __restrict__ b2,
    const float* __restrict__ gamma, const float* __restrict__ beta,
    const int* __restrict__ conArr,
    int* csr_off, int* csr_cur, int* csr_v,
    float* dinvC, float* nodeval, int* breakix,
    float* S1, float* outvar, float* holo,
    int* RnG, float* RwG, int* nRG, float* dz2G,
    float* out, int phase)
{
    __shared__ float smemf[14848];   // 59392 B, aliased per phase
    __shared__ int nR_s;
    const bool coop = (phase < 0);
    int bid = blockIdx.x;

    // P0: setup (graph-local)
    if ((coop || phase == 0) && bid < G_)
        setup_body(bid, conArr, csr_off, csr_cur, dinvC, nodeval, breakix, smemf);
    if (coop) cg::this_grid().sync();

    // P1: chip-wide CSR fill
    if (coop || phase == 1) {
        int e = bid*1024 + threadIdx.x;
        if (e < NE) { int p = atomicAdd(&csr_cur[conArr[e]], 1); csr_v[p] = e >> 3; }
    }
    if (coop) cg::this_grid().sync();

    // P2: f1 (spmmX + gemm1)
    if (coop || phase == 2) {
        if (coop) {
            f1_body(bid, true, vf, cf, dinvC, conArr, csr_off, csr_v, W1, b1, nodeval, S1, smemf);
            int t2 = (bid < F1_TILES - MEGA_GRID) ? MEGA_GRID + bid : -1;   // 244 blocks get 2nd tile
            if (t2 >= 0)
                f1_body(t2, false, vf, cf, dinvC, conArr, csr_off, csr_v, W1, b1, nodeval, S1, smemf);
        } else {
            f1_body(bid, true, vf, cf, dinvC, conArr, csr_off, csr_v, W1, b1, nodeval, S1, smemf);
        }
    }
    if (coop) cg::this_grid().sync();

    // P3: f2 (spmmH + gemm2 + LN) and corr_a tiles
    if (coop || phase == 3) {
        if (coop) {
            f2gemm_body(bid, true, S1, dinvC, conArr, W2, b2, nodeval, gamma, beta,
                        outvar, holo, out, smemf);
            int t2 = (bid < F2_TILES - MEGA_GRID) ? MEGA_GRID + bid : -1;   // 256..406
            if (t2 >= 0) {
                if (t2 < F2_GEMM_TILES)
                    f2gemm_body(t2, false, S1, dinvC, conArr, W2, b2, nodeval, gamma, beta,
                                outvar, holo, out, smemf);
                else
                    corra_body(t2 - F2_GEMM_TILES, S1, dinvC, conArr, csr_off, csr_v,
                               W1, W2, breakix, RnG, RwG, nRG, dz2G, smemf, nR_s);
            }
        } else {
            if (bid < F2_GEMM_TILES)
                f2gemm_body(bid, true, S1, dinvC, conArr, W2, b2, nodeval, gamma, beta,
                            outvar, holo, out, smemf);
            else
                corra_body(bid - F2_GEMM_TILES, S1, dinvC, conArr, csr_off, csr_v,
                           W1, W2, breakix, RnG, RwG, nRG, dz2G, smemf, nR_s);
        }
    }
    if (coop) cg::this_grid().sync();

    // P4: corr_b
    if ((coop || phase == 4) && bid < NB)
        corrb_body(bid, RnG, RwG, nRG, dz2G, breakix, dinvC, conArr, csr_off, csr_v,
                   outvar, holo, gamma, beta, out, smemf);
}

// ================= launch =================

extern "C" void kernel_launch(void* const* d_in, const int* in_sizes, int n_in,
                              void* d_out, int out_size, void* d_ws, size_t ws_size,
                              hipStream_t stream) {
    const float* vf    = (const float*)d_in[0];
    const float* cf    = (const float*)d_in[1];
    const float* W1    = (const float*)d_in[2];
    const float* b1    = (const float*)d_in[3];
    const float* W2    = (const float*)d_in[4];
    const float* b2    = (const float*)d_in[5];
    const float* gamma = (const float*)d_in[6];
    const float* beta  = (const float*)d_in[7];
    const int*   conArr = (const int*)d_in[8];
    float* out = (float*)d_out;

    char* ws = (char*)d_ws;
    size_t off = 0;
    auto alloc = [&](size_t bytes) { char* p = ws + off; off = (off + bytes + 255) & ~(size_t)255; return p; };
    float* dinvC   = (float*)alloc(NC*4);
    int*   csr_off = (int*)  alloc((NC+1)*4);
    int*   csr_cur = (int*)  alloc(NC*4);
    int*   csr_v   = (int*)  alloc(NE*4);
    float* nodeval = (float*)alloc(NN*4);
    int*   breakix = (int*)  alloc(NB*4);
    float* S1      = (float*)alloc((size_t)NN*DH*4);
    float* outvar  = (float*)alloc((size_t)NV*DO*4);
    float* holo    = (float*)alloc((size_t)NV*DO*4);
    int*   RnG     = (int*)  alloc(NB*MAXR*4);
    float* RwG     = (float*)alloc(NB*MAXR*4);
    int*   nRG     = (int*)  alloc(NB*4);
    float* dz2G    = (float*)alloc((size_t)NB*MAXR*DO*4);

    bool useCoop = false;
    int occ = 0;
    if (hipOccupancyMaxActiveBlocksPerMultiprocessor(&occ, (const void*)k_mega, 1024, 0) == hipSuccess
        && occ >= 1) {
        int ph = -1;
        void* args[] = {
            (void*)&vf, (void*)&cf, (void*)&W1, (void*)&b1, (void*)&W2, (void*)&b2,
            (void*)&gamma, (void*)&beta, (void*)&conArr,
            (void*)&csr_off, (void*)&csr_cur, (void*)&csr_v,
            (void*)&dinvC, (void*)&nodeval, (void*)&breakix,
            (void*)&S1, (void*)&outvar, (void*)&holo,
            (void*)&RnG, (void*)&RwG, (void*)&nRG, (void*)&dz2G,
            (void*)&out, (void*)&ph };
        if (hipLaunchCooperativeKernel((const void*)k_mega, dim3(MEGA_GRID), dim3(1024),
                                       args, 0, stream) == hipSuccess)
            useCoop = true;
        else
            (void)hipGetLastError();
    }

    if (!useCoop) {
        k_mega<<<G_,                1024, 0, stream>>>(vf, cf, W1, b1, W2, b2, gamma, beta, conArr,
            csr_off, csr_cur, csr_v, dinvC, nodeval, breakix, S1, outvar, holo,
            RnG, RwG, nRG, dz2G, out, 0);
        k_mega<<<(NE+1023)/1024,    1024, 0, stream>>>(vf, cf, W1, b1, W2, b2, gamma, beta, conArr,
            csr_off, csr_cur, csr_v, dinvC, nodeval, breakix, S1, outvar, holo,
            RnG, RwG, nRG, dz2G, out, 1);
        k_mega<<<F1_TILES,          1024, 0, stream>>>(vf, cf, W1, b1, W2, b2, gamma, beta, conArr,
            csr_off, csr_cur, csr_v, dinvC, nodeval, breakix, S1, outvar, holo,
            RnG, RwG, nRG, dz2G, out, 2);
        k_mega<<<F2_TILES,          1024, 0, stream>>>(vf, cf, W1, b1, W2, b2, gamma, beta, conArr,
            csr_off, csr_cur, csr_v, dinvC, nodeval, breakix, S1, outvar, holo,
            RnG, RwG, nRG, dz2G, out, 3);
        k_mega<<<NB,                1024, 0, stream>>>(vf, cf, W1, b1, W2, b2, gamma, beta, conArr,
            csr_off, csr_cur, csr_v, dinvC, nodeval, breakix, S1, outvar, holo,
            RnG, RwG, nRG, dz2G, out, 4);
    }
}